// Round 1
// baseline (1043.488 us; speedup 1.0000x reference)
//
#include <hip/hip_runtime.h>

// ---------- types ----------
typedef __bf16 vbf8 __attribute__((ext_vector_type(8)));
typedef unsigned short us8 __attribute__((ext_vector_type(8)));
typedef float f32x4 __attribute__((ext_vector_type(4)));

__device__ __forceinline__ unsigned short f2bf(float f) {
  unsigned u = __float_as_uint(f);
  u += 0x7FFFu + ((u >> 16) & 1u);           // RNE
  return (unsigned short)(u >> 16);
}

__device__ __forceinline__ void fma4(float4& a, float s, const float4 w) {
  a.x = fmaf(s, w.x, a.x); a.y = fmaf(s, w.y, a.y);
  a.z = fmaf(s, w.z, a.z); a.w = fmaf(s, w.w, a.w);
}

// ---------------------------------------------------------------------------
// Stage A: pillar feature net (bf16 MFMA), masked max over points,
// per-wave partial sums for the pillar mean.
// One wave per pillar; wave wgid in [0,3000): b = wgid/750, handles pillars
// p = (wgid%750) + 750*i, i in [0,16).
// ---------------------------------------------------------------------------
__global__ __launch_bounds__(256) void pillar_kernel(
    const float* __restrict__ pil, const int* __restrict__ npt,
    const float* __restrict__ w1, const float* __restrict__ b1,
    const float* __restrict__ s1, const float* __restrict__ t1,
    const float* __restrict__ w2, const float* __restrict__ b2,
    const float* __restrict__ s2, const float* __restrict__ t2,
    float* __restrict__ partial, int* __restrict__ pcnt)
{
  __shared__ unsigned short ldsa[4][16 * 72];
  const int tid = threadIdx.x;
  const int wv = tid >> 6, lane = tid & 63;
  const int s = lane & 15, g = lane >> 4;
  unsigned short* lds = ldsa[wv];
  const int wgid = blockIdx.x * 4 + wv;
  const int b = wgid / 750;
  const int p0 = wgid - b * 750;

  // preload weight fragments (B-operand: row k=(l>>4)*8+e, col n=l&15)
  vbf8 w1f[4], w2f[2][4];
  float a1[4], be1[4], a2[4], be2[4];
#pragma unroll
  for (int n = 0; n < 4; ++n) {
    us8 u1, u20, u21;
#pragma unroll
    for (int e = 0; e < 8; ++e) {
      int k = g * 8 + e;
      int co = s + 16 * n;
      u1[e] = (k < 9) ? f2bf(w1[k * 64 + co]) : (unsigned short)0;
      u20[e] = f2bf(w2[k * 64 + co]);
      u21[e] = f2bf(w2[(32 + k) * 64 + co]);
    }
    w1f[n] = __builtin_bit_cast(vbf8, u1);
    w2f[0][n] = __builtin_bit_cast(vbf8, u20);
    w2f[1][n] = __builtin_bit_cast(vbf8, u21);
    int c = s + 16 * n;
    a1[n] = s1[c]; be1[n] = fmaf(b1[c], s1[c], t1[c]);
    a2[n] = s2[c]; be2[n] = fmaf(b2[c], s2[c], t2[c]);
  }

  float fsum[4] = {0.f, 0.f, 0.f, 0.f};
  int cnt = 0;

  for (int i = 0; i < 16; ++i) {
    int p = p0 + 750 * i;
    int pidx = b * 12000 + p;
    int np = npt[pidx];
    if (np <= 0) continue;     // wave-uniform
    ++cnt;
    float feat[4][4];
#pragma unroll
    for (int n = 0; n < 4; ++n)
#pragma unroll
      for (int r = 0; r < 4; ++r) feat[n][r] = 0.f;

    int ngrp = (np + 15) >> 4;
    const float* pbase = pil + (size_t)pidx * 900;
    for (int grp = 0; grp < ngrp; ++grp) {
      // A1 fragment: point row = s, k = g*8+e (zero-pad k>=9)
      vbf8 af;
      {
        const float* ptp = pbase + (grp * 16 + s) * 9;
        us8 ua;
#pragma unroll
        for (int e = 0; e < 8; ++e) {
          int k = g * 8 + e;
          ua[e] = (k < 9) ? f2bf(ptp[k]) : (unsigned short)0;
        }
        af = __builtin_bit_cast(vbf8, ua);
      }
      const f32x4 z = {0.f, 0.f, 0.f, 0.f};
      f32x4 d1[4];
#pragma unroll
      for (int n = 0; n < 4; ++n)
        d1[n] = __builtin_amdgcn_mfma_f32_16x16x32_bf16(af, w1f[n], z, 0, 0, 0);

      // bn1+relu, bf16, LDS transpose write [pt][ch] (XOR swizzle for banks)
#pragma unroll
      for (int n = 0; n < 4; ++n)
#pragma unroll
        for (int r = 0; r < 4; ++r) {
          float h = fmaxf(fmaf(d1[n][r], a1[n], be1[n]), 0.f);
          int pt = g * 4 + r;
          int ch = (s + 16 * n) ^ ((pt >> 2) << 3);
          lds[pt * 72 + ch] = f2bf(h);
        }
      asm volatile("s_waitcnt lgkmcnt(0)" ::: "memory");
      __builtin_amdgcn_sched_barrier(0);

      // A2 fragments: pt = s, ch = kt*32 + g*8 + e
      vbf8 a2f[2];
#pragma unroll
      for (int kt = 0; kt < 2; ++kt) {
        int chb = (kt * 32 + g * 8) ^ ((s >> 2) << 3);
        a2f[kt] = __builtin_bit_cast(vbf8, *(const us8*)(lds + s * 72 + chb));
      }
      f32x4 d2[4];
#pragma unroll
      for (int n = 0; n < 4; ++n) {
        d2[n] = __builtin_amdgcn_mfma_f32_16x16x32_bf16(a2f[0], w2f[0][n], z, 0, 0, 0);
        d2[n] = __builtin_amdgcn_mfma_f32_16x16x32_bf16(a2f[1], w2f[1][n], d2[n], 0, 0, 0);
      }
      // bn2+relu, masked max
#pragma unroll
      for (int n = 0; n < 4; ++n)
#pragma unroll
        for (int r = 0; r < 4; ++r) {
          float h = fmaxf(fmaf(d2[n][r], a2[n], be2[n]), 0.f);
          if (grp * 16 + g * 4 + r < np) feat[n][r] = fmaxf(feat[n][r], h);
        }
    }
    // reduce feat over point rows (r regs, then lane groups)
#pragma unroll
    for (int n = 0; n < 4; ++n) {
      float m = fmaxf(fmaxf(feat[n][0], feat[n][1]), fmaxf(feat[n][2], feat[n][3]));
      m = fmaxf(m, __shfl_xor(m, 16));
      m = fmaxf(m, __shfl_xor(m, 32));
      fsum[n] += m;
    }
  }
  if (g == 0) {
#pragma unroll
    for (int n = 0; n < 4; ++n) partial[wgid * 64 + s + 16 * n] = fsum[n];
    if (s == 0) pcnt[wgid] = cnt;
  }
}

// finish the mean: 4 blocks (one per batch)
__global__ void mean_kernel(const float* __restrict__ partial,
                            const int* __restrict__ pcnt,
                            float* __restrict__ mean) {
  int b = blockIdx.x, t = threadIdx.x;
  int c = t & 63, q = t >> 6;
  float sum = 0.f;
  for (int w = q; w < 750; w += 4) sum += partial[(b * 750 + w) * 64 + c];
  int cl = 0;
  for (int w = t; w < 750; w += 256) cl += pcnt[b * 750 + w];
  __shared__ float sh[256];
  __shared__ int shc[256];
  sh[t] = sum; shc[t] = cl;
  __syncthreads();
  for (int o = 128; o > 0; o >>= 1) {
    if (t < o) shc[t] += shc[t + o];
    __syncthreads();
  }
  if (t < 64) {
    float tot = sh[t] + sh[t + 64] + sh[t + 128] + sh[t + 192];
    mean[b * 64 + t] = tot / (float)(shc[0] > 0 ? shc[0] : 1);
  }
}

// broadcast mean -> x0 [b][64][64][64ch] NHWC (reduced 64x64 grid)
__global__ void broadcast_kernel(const float* __restrict__ mean,
                                 float* __restrict__ x0) {
  int f = blockIdx.x * 256 + threadIdx.x;   // 262144 float4s
  int c4 = f & 15; int b = f >> 16;
  float4 v = *(const float4*)(mean + b * 64 + c4 * 4);
  ((float4*)x0)[f] = v;
}

// ---------------------------------------------------------------------------
// fp32 NHWC conv3x3 SAME + (folded BN | bias) + optional ReLU
// threads: cq = t % (COUT/4) (channel quad, fastest -> coalesced), wi = t / NQ
// ---------------------------------------------------------------------------
template <int CIN, int COUT, int HW, bool RELU, bool HAS_BN>
__global__ __launch_bounds__(256) void conv3x3_kernel(
    const float* __restrict__ x, const float* __restrict__ wgt,
    const float* __restrict__ cb, const float* __restrict__ cs,
    const float* __restrict__ ct, float* __restrict__ y)
{
  constexpr int NQ = COUT / 4;
  constexpr int WPB = 256 / NQ;
  const int t = threadIdx.x;
  const int cq = t % NQ;
  const int wi = t / NQ;
  const int w = blockIdx.x * WPB + wi;
  const int co0 = cq * 4;
  const int h = blockIdx.y;
  const int b = blockIdx.z;
  const float* xb = x + (size_t)b * HW * HW * CIN;
  float4 acc = make_float4(0.f, 0.f, 0.f, 0.f);
#pragma unroll
  for (int dh = -1; dh <= 1; ++dh) {
    int hh = h + dh;
    if (hh < 0 || hh >= HW) continue;
#pragma unroll
    for (int dw = -1; dw <= 1; ++dw) {
      int ww = w + dw;
      bool vld = (ww >= 0) && (ww < HW);
      const float* xr = xb + ((size_t)hh * HW + (vld ? ww : 0)) * CIN;
      const float* wr = wgt + (size_t)((dh + 1) * 3 + (dw + 1)) * CIN * COUT + co0;
#pragma unroll 2
      for (int ci = 0; ci < CIN; ci += 4) {
        float4 in4 = vld ? *(const float4*)(xr + ci) : make_float4(0.f, 0.f, 0.f, 0.f);
        fma4(acc, in4.x, *(const float4*)(wr + (size_t)(ci + 0) * COUT));
        fma4(acc, in4.y, *(const float4*)(wr + (size_t)(ci + 1) * COUT));
        fma4(acc, in4.z, *(const float4*)(wr + (size_t)(ci + 2) * COUT));
        fma4(acc, in4.w, *(const float4*)(wr + (size_t)(ci + 3) * COUT));
      }
    }
  }
  float4 res;
  if (HAS_BN) {
    float4 sc = *(const float4*)(cs + co0);
    float4 bb = *(const float4*)(cb + co0);
    float4 tt = *(const float4*)(ct + co0);
    res.x = fmaf(acc.x, sc.x, fmaf(bb.x, sc.x, tt.x));
    res.y = fmaf(acc.y, sc.y, fmaf(bb.y, sc.y, tt.y));
    res.z = fmaf(acc.z, sc.z, fmaf(bb.z, sc.z, tt.z));
    res.w = fmaf(acc.w, sc.w, fmaf(bb.w, sc.w, tt.w));
  } else {
    float4 bb = *(const float4*)(cb + co0);
    res.x = acc.x + bb.x; res.y = acc.y + bb.y;
    res.z = acc.z + bb.z; res.w = acc.w + bb.w;
  }
  if (RELU) {
    res.x = fmaxf(res.x, 0.f); res.y = fmaxf(res.y, 0.f);
    res.z = fmaxf(res.z, 0.f); res.w = fmaxf(res.w, 0.f);
  }
  float* yp = y + ((size_t)(b * HW + h) * HW + w) * COUT + co0;
  *(float4*)yp = res;
}

// 2x2 max pool, NHWC
template <int C, int HWI>
__global__ void pool_kernel(const float* __restrict__ x, float* __restrict__ y) {
  constexpr int HO = HWI / 2;
  constexpr int C4 = C / 4;
  int f = blockIdx.x * 256 + threadIdx.x;
  int c4 = f % C4; int rest = f / C4;
  int wo = rest % HO; rest /= HO;
  int ho = rest % HO; int b = rest / HO;
  const float* p = x + (((size_t)(b * HWI + 2 * ho) * HWI) + 2 * wo) * C + c4 * 4;
  float4 a = *(const float4*)p;
  float4 b2 = *(const float4*)(p + C);
  float4 c2 = *(const float4*)(p + (size_t)HWI * C);
  float4 d2 = *(const float4*)(p + (size_t)HWI * C + C);
  float4 m;
  m.x = fmaxf(fmaxf(a.x, b2.x), fmaxf(c2.x, d2.x));
  m.y = fmaxf(fmaxf(a.y, b2.y), fmaxf(c2.y, d2.y));
  m.z = fmaxf(fmaxf(a.z, b2.z), fmaxf(c2.z, d2.z));
  m.w = fmaxf(fmaxf(a.w, b2.w), fmaxf(c2.w, d2.w));
  float* yp = y + ((size_t)(b * HO + ho) * HO + wo) * C + c4 * 4;
  *(float4*)yp = m;
}

// 1x1 conv 256 -> 10 + bias (no relu), 16x16 spatial
__global__ void head2_kernel(const float* __restrict__ x, const float* __restrict__ wk,
                             const float* __restrict__ bias, float* __restrict__ y) {
  int h = blockIdx.x, b = blockIdx.y;
  int t = threadIdx.x;
  int co = t & 15, w = t >> 4;
  if (co >= 10) return;
  const float* xr = x + ((size_t)(b * 16 + h) * 16 + w) * 256;
  float acc = 0.f;
#pragma unroll 4
  for (int ci = 0; ci < 256; ci += 4) {
    float4 in4 = *(const float4*)(xr + ci);
    acc = fmaf(in4.x, wk[(ci + 0) * 10 + co], acc);
    acc = fmaf(in4.y, wk[(ci + 1) * 10 + co], acc);
    acc = fmaf(in4.z, wk[(ci + 2) * 10 + co], acc);
    acc = fmaf(in4.w, wk[(ci + 3) * 10 + co], acc);
  }
  y[((size_t)(b * 16 + h) * 16 + w) * 10 + co] = acc + bias[co];
}

// scatter reduced 16x16 head output -> full 27x31 NCHW output
__global__ void scatter_kernel(const float* __restrict__ y, float* __restrict__ out) {
  int idx = blockIdx.x * 256 + threadIdx.x;
  if (idx >= 4 * 10 * 27 * 31) return;
  int c = idx % 31;
  int r = (idx / 31) % 27;
  int ch = (idx / (31 * 27)) % 10;
  int b = idx / (31 * 27 * 10);
  int rr = (r <= 7) ? r : ((r >= 20) ? r - 11 : 7);
  int cc = (c <= 7) ? c : ((c >= 24) ? c - 15 : 7);
  out[idx] = y[((size_t)(b * 16 + rr) * 16 + cc) * 10 + ch];
}

// ---------------------------------------------------------------------------
extern "C" void kernel_launch(void* const* d_in, const int* in_sizes, int n_in,
                              void* d_out, int out_size, void* d_ws, size_t ws_size,
                              hipStream_t stream) {
  (void)in_sizes; (void)n_in; (void)out_size; (void)ws_size;
  const float* pillars = (const float*)d_in[0];
  const float* w1 = (const float*)d_in[1];
  const float* b1 = (const float*)d_in[2];
  const float* s1 = (const float*)d_in[3];
  const float* t1 = (const float*)d_in[4];
  const float* w2 = (const float*)d_in[5];
  const float* b2 = (const float*)d_in[6];
  const float* s2 = (const float*)d_in[7];
  const float* t2 = (const float*)d_in[8];
  const float* ck[6], *cbv[6], *csv[6], *ctv[6];
  for (int i = 0; i < 6; ++i) {
    ck[i]  = (const float*)d_in[9 + i * 4];
    cbv[i] = (const float*)d_in[10 + i * 4];
    csv[i] = (const float*)d_in[11 + i * 4];
    ctv[i] = (const float*)d_in[12 + i * 4];
  }
  const float* hk1 = (const float*)d_in[33];
  const float* hb1 = (const float*)d_in[34];
  const float* hk2 = (const float*)d_in[35];
  const float* hb2 = (const float*)d_in[36];
  const int* num_points = (const int*)d_in[37];
  float* out = (float*)d_out;

  char* ws = (char*)d_ws;
  float* partial = (float*)(ws + 0);            // 3000*64*4   = 768000 B
  int*   pcnt    = (int*)(ws + 768000);         // 3000*4      = 12000 B
  float* mean    = (float*)(ws + 780032);       // 4*64*4      = 1024 B
  float* bufA    = (float*)(ws + (1u << 20));   // 4.19 MB
  float* bufB    = (float*)(ws + (6u << 20));   // 4.19 MB

  pillar_kernel<<<750, 256, 0, stream>>>(pillars, num_points, w1, b1, s1, t1,
                                         w2, b2, s2, t2, partial, pcnt);
  mean_kernel<<<4, 256, 0, stream>>>(partial, pcnt, mean);
  broadcast_kernel<<<1024, 256, 0, stream>>>(mean, bufA);

  conv3x3_kernel<64, 64, 64, true, true><<<dim3(4, 64, 4), 256, 0, stream>>>(
      bufA, ck[0], cbv[0], csv[0], ctv[0], bufB);
  conv3x3_kernel<64, 64, 64, true, true><<<dim3(4, 64, 4), 256, 0, stream>>>(
      bufB, ck[1], cbv[1], csv[1], ctv[1], bufA);
  pool_kernel<64, 64><<<256, 256, 0, stream>>>(bufA, bufB);
  conv3x3_kernel<64, 128, 32, true, true><<<dim3(4, 32, 4), 256, 0, stream>>>(
      bufB, ck[2], cbv[2], csv[2], ctv[2], bufA);
  conv3x3_kernel<128, 128, 32, true, true><<<dim3(4, 32, 4), 256, 0, stream>>>(
      bufA, ck[3], cbv[3], csv[3], ctv[3], bufB);
  pool_kernel<128, 32><<<128, 256, 0, stream>>>(bufB, bufA);
  conv3x3_kernel<128, 256, 16, true, true><<<dim3(4, 16, 4), 256, 0, stream>>>(
      bufA, ck[4], cbv[4], csv[4], ctv[4], bufB);
  conv3x3_kernel<256, 256, 16, true, true><<<dim3(4, 16, 4), 256, 0, stream>>>(
      bufB, ck[5], cbv[5], csv[5], ctv[5], bufA);
  conv3x3_kernel<256, 256, 16, true, false><<<dim3(4, 16, 4), 256, 0, stream>>>(
      bufA, hk1, hb1, nullptr, nullptr, bufB);
  head2_kernel<<<dim3(16, 4), 256, 0, stream>>>(bufB, hk2, hb2, bufA);
  scatter_kernel<<<131, 256, 0, stream>>>(bufA, out);
}

// Round 2
// 936.783 us; speedup vs baseline: 1.1139x; 1.1139x over previous
//
#include <hip/hip_runtime.h>

// ---------- types ----------
typedef __bf16 vbf8 __attribute__((ext_vector_type(8)));
typedef unsigned short us8 __attribute__((ext_vector_type(8)));
typedef float f32x4 __attribute__((ext_vector_type(4)));

__device__ __forceinline__ unsigned short f2bf(float f) {
  unsigned u = __float_as_uint(f);
  u += 0x7FFFu + ((u >> 16) & 1u);           // RNE
  return (unsigned short)(u >> 16);
}

__device__ __forceinline__ void fma4(float4& a, float s, const float4 w) {
  a.x = fmaf(s, w.x, a.x); a.y = fmaf(s, w.y, a.y);
  a.z = fmaf(s, w.z, a.z); a.w = fmaf(s, w.w, a.w);
}

// ---------------------------------------------------------------------------
// setup: precompute bf16 MFMA weight fragments + folded BN coeffs per lane.
// wfrag[12][64][8] shorts, cfrag[4][64] float4 (a1,be1,a2,be2).
// ---------------------------------------------------------------------------
__global__ void setup_kernel(const float* __restrict__ w1, const float* __restrict__ b1,
                             const float* __restrict__ s1, const float* __restrict__ t1,
                             const float* __restrict__ w2, const float* __restrict__ b2,
                             const float* __restrict__ s2, const float* __restrict__ t2,
                             unsigned short* __restrict__ wfrag, float4* __restrict__ cfrag) {
  int l = threadIdx.x;                       // 0..63
  int s = l & 15, g = l >> 4;
#pragma unroll
  for (int n = 0; n < 4; ++n) {
    int co = s + 16 * n;
#pragma unroll
    for (int e = 0; e < 8; ++e) {
      int k = g * 8 + e;
      wfrag[(n * 64 + l) * 8 + e] = (k < 9) ? f2bf(w1[k * 64 + co]) : (unsigned short)0;
      wfrag[((4 + n) * 64 + l) * 8 + e] = f2bf(w2[k * 64 + co]);
      wfrag[((8 + n) * 64 + l) * 8 + e] = f2bf(w2[(32 + k) * 64 + co]);
    }
    cfrag[n * 64 + l] = make_float4(s1[co], fmaf(b1[co], s1[co], t1[co]),
                                    s2[co], fmaf(b2[co], s2[co], t2[co]));
  }
}

// ---------------------------------------------------------------------------
// Stage A: pillar feature net (bf16 MFMA), masked max, block partial sums.
// 2 pillars per wave; 6000 blocks x 4 waves = 24000 waves = 48000 pillars.
// ---------------------------------------------------------------------------
__global__ __launch_bounds__(256) void pillar_kernel(
    const float* __restrict__ pil, const int* __restrict__ npt,
    const unsigned short* __restrict__ wfrag, const float4* __restrict__ cfrag,
    float* __restrict__ partial, int* __restrict__ pcnt)
{
  __shared__ unsigned short ldsa[4][16 * 72];
  __shared__ float redf[4][64];
  __shared__ int redc[4];
  const int tid = threadIdx.x;
  const int wv = tid >> 6, lane = tid & 63;
  const int s = lane & 15, g = lane >> 4;
  unsigned short* lds = ldsa[wv];
  const int wid = blockIdx.x * 4 + wv;       // 0..23999
  const int b = wid / 6000;
  const int p0 = (wid - b * 6000) * 2;

  vbf8 w1f[4], w2f[2][4];
  float a1[4], be1[4], a2[4], be2[4];
#pragma unroll
  for (int n = 0; n < 4; ++n) {
    w1f[n]    = __builtin_bit_cast(vbf8, *(const us8*)(wfrag + ((0 + n) * 64 + lane) * 8));
    w2f[0][n] = __builtin_bit_cast(vbf8, *(const us8*)(wfrag + ((4 + n) * 64 + lane) * 8));
    w2f[1][n] = __builtin_bit_cast(vbf8, *(const us8*)(wfrag + ((8 + n) * 64 + lane) * 8));
    float4 c = cfrag[n * 64 + lane];
    a1[n] = c.x; be1[n] = c.y; a2[n] = c.z; be2[n] = c.w;
  }

  float fsum[4] = {0.f, 0.f, 0.f, 0.f};
  int cnt = 0;

  for (int i = 0; i < 2; ++i) {
    int pidx = b * 12000 + p0 + i;
    int np = npt[pidx];
    if (np <= 0) continue;     // wave-uniform
    ++cnt;
    float feat[4][4];
#pragma unroll
    for (int n = 0; n < 4; ++n)
#pragma unroll
      for (int r = 0; r < 4; ++r) feat[n][r] = 0.f;

    int ngrp = (np + 15) >> 4;
    const float* pbase = pil + (size_t)pidx * 900;
    for (int grp = 0; grp < ngrp; ++grp) {
      // A1 fragment: point row = s, k = g*8+e (zero-pad k>=9)
      vbf8 af;
      {
        int pt = grp * 16 + s; if (pt > 99) pt = 99;   // clamp (OOB guard)
        const float* ptp = pbase + pt * 9;
        us8 ua;
#pragma unroll
        for (int e = 0; e < 8; ++e) {
          int k = g * 8 + e;
          ua[e] = (k < 9) ? f2bf(ptp[k]) : (unsigned short)0;
        }
        af = __builtin_bit_cast(vbf8, ua);
      }
      const f32x4 z = {0.f, 0.f, 0.f, 0.f};
      f32x4 d1[4];
#pragma unroll
      for (int n = 0; n < 4; ++n)
        d1[n] = __builtin_amdgcn_mfma_f32_16x16x32_bf16(af, w1f[n], z, 0, 0, 0);

      // bn1+relu, bf16, LDS transpose write [pt][ch] (XOR swizzle for banks)
#pragma unroll
      for (int n = 0; n < 4; ++n)
#pragma unroll
        for (int r = 0; r < 4; ++r) {
          float h = fmaxf(fmaf(d1[n][r], a1[n], be1[n]), 0.f);
          int pt = g * 4 + r;
          int ch = (s + 16 * n) ^ ((pt >> 2) << 3);
          lds[pt * 72 + ch] = f2bf(h);
        }
      asm volatile("s_waitcnt lgkmcnt(0)" ::: "memory");
      __builtin_amdgcn_sched_barrier(0);

      // A2 fragments: pt = s, ch = kt*32 + g*8 + e
      vbf8 a2f[2];
#pragma unroll
      for (int kt = 0; kt < 2; ++kt) {
        int chb = (kt * 32 + g * 8) ^ ((s >> 2) << 3);
        a2f[kt] = __builtin_bit_cast(vbf8, *(const us8*)(lds + s * 72 + chb));
      }
      f32x4 d2[4];
#pragma unroll
      for (int n = 0; n < 4; ++n) {
        d2[n] = __builtin_amdgcn_mfma_f32_16x16x32_bf16(a2f[0], w2f[0][n], z, 0, 0, 0);
        d2[n] = __builtin_amdgcn_mfma_f32_16x16x32_bf16(a2f[1], w2f[1][n], d2[n], 0, 0, 0);
      }
      // bn2+relu, masked max
#pragma unroll
      for (int n = 0; n < 4; ++n)
#pragma unroll
        for (int r = 0; r < 4; ++r) {
          float h = fmaxf(fmaf(d2[n][r], a2[n], be2[n]), 0.f);
          if (grp * 16 + g * 4 + r < np) feat[n][r] = fmaxf(feat[n][r], h);
        }
    }
    // reduce feat over point rows (r regs, then lane groups)
#pragma unroll
    for (int n = 0; n < 4; ++n) {
      float m = fmaxf(fmaxf(feat[n][0], feat[n][1]), fmaxf(feat[n][2], feat[n][3]));
      m = fmaxf(m, __shfl_xor(m, 16));
      m = fmaxf(m, __shfl_xor(m, 32));
      fsum[n] += m;
    }
  }
  if (g == 0) {
#pragma unroll
    for (int n = 0; n < 4; ++n) redf[wv][s + 16 * n] = fsum[n];
  }
  if (lane == 0) redc[wv] = cnt;
  __syncthreads();
  if (tid < 64) {
    float tot = redf[0][tid] + redf[1][tid] + redf[2][tid] + redf[3][tid];
    partial[blockIdx.x * 64 + tid] = tot;
    if (tid == 0) pcnt[blockIdx.x] = redc[0] + redc[1] + redc[2] + redc[3];
  }
}

// finish the mean: 4 blocks (one per batch), 1500 partial blocks each
__global__ void mean_kernel(const float* __restrict__ partial,
                            const int* __restrict__ pcnt,
                            float* __restrict__ mean) {
  int b = blockIdx.x, t = threadIdx.x;
  int c = t & 63, q = t >> 6;
  float sum = 0.f;
  for (int w = q; w < 1500; w += 4) sum += partial[(b * 1500 + w) * 64 + c];
  int cl = 0;
  for (int w = t; w < 1500; w += 256) cl += pcnt[b * 1500 + w];
  __shared__ float sh[256];
  __shared__ int shc[256];
  sh[t] = sum; shc[t] = cl;
  __syncthreads();
  for (int o = 128; o > 0; o >>= 1) {
    if (t < o) shc[t] += shc[t + o];
    __syncthreads();
  }
  if (t < 64) {
    float tot = sh[t] + sh[t + 64] + sh[t + 128] + sh[t + 192];
    mean[b * 64 + t] = tot / (float)(shc[0] > 0 ? shc[0] : 1);
  }
}

// broadcast mean -> x0 [b][64][64][64ch] NHWC (reduced 64x64 grid)
__global__ void broadcast_kernel(const float* __restrict__ mean,
                                 float* __restrict__ x0) {
  int f = blockIdx.x * 256 + threadIdx.x;   // 262144 float4s
  int c4 = f & 15; int b = f >> 16;
  float4 v = *(const float4*)(mean + b * 64 + c4 * 4);
  ((float4*)x0)[f] = v;
}

// ---------------------------------------------------------------------------
// fp32 NHWC conv3x3 SAME + (folded BN | bias) + optional ReLU.
// WPT output w-positions per thread with shared taps.
// thread: cq = t % (COUT/4) (fastest -> coalesced), wi = t / NQ.
// grid: x = HW/(WGRP*WPT), y = HW, z = B.
// ---------------------------------------------------------------------------
template <int CIN, int COUT, int HW, int WPT, bool RELU, bool HAS_BN>
__global__ __launch_bounds__(256) void conv3x3_kernel(
    const float* __restrict__ x, const float* __restrict__ wgt,
    const float* __restrict__ cb, const float* __restrict__ cs,
    const float* __restrict__ ct, float* __restrict__ y)
{
  constexpr int NQ = COUT / 4;
  constexpr int WGRP = 256 / NQ;
  const int t = threadIdx.x;
  const int cq = t % NQ;
  const int wi = t / NQ;
  const int w0 = (blockIdx.x * WGRP + wi) * WPT;
  const int co0 = cq * 4;
  const int h = blockIdx.y;
  const int b = blockIdx.z;
  const float* xb = x + (size_t)b * HW * HW * CIN;
  float4 acc[WPT];
#pragma unroll
  for (int j = 0; j < WPT; ++j) acc[j] = make_float4(0.f, 0.f, 0.f, 0.f);

#pragma unroll
  for (int dh = 0; dh < 3; ++dh) {
    int hh = h + dh - 1;
    if (hh < 0 || hh >= HW) continue;          // uniform per block
    const float* xrow = xb + (size_t)hh * HW * CIN;
    const float* wrow = wgt + (size_t)dh * 3 * CIN * COUT;
#pragma unroll 2
    for (int ci = 0; ci < CIN; ci += 4) {
      float4 in[WPT + 2];
#pragma unroll
      for (int c = 0; c < WPT + 2; ++c) {
        int col = w0 + c - 1;
        bool v = (col >= 0) && (col < HW);
        in[c] = v ? *(const float4*)(xrow + (size_t)col * CIN + ci)
                  : make_float4(0.f, 0.f, 0.f, 0.f);
      }
#pragma unroll
      for (int dw = 0; dw < 3; ++dw) {
        const float* wr = wrow + ((size_t)dw * CIN + ci) * COUT + co0;
        float4 wq0 = *(const float4*)(wr);
        float4 wq1 = *(const float4*)(wr + COUT);
        float4 wq2 = *(const float4*)(wr + 2 * COUT);
        float4 wq3 = *(const float4*)(wr + 3 * COUT);
#pragma unroll
        for (int j = 0; j < WPT; ++j) {
          float4 v = in[j + dw];
          fma4(acc[j], v.x, wq0); fma4(acc[j], v.y, wq1);
          fma4(acc[j], v.z, wq2); fma4(acc[j], v.w, wq3);
        }
      }
    }
  }
#pragma unroll
  for (int j = 0; j < WPT; ++j) {
    float4 res;
    if (HAS_BN) {
      float4 sc = *(const float4*)(cs + co0);
      float4 bb = *(const float4*)(cb + co0);
      float4 tt = *(const float4*)(ct + co0);
      res.x = fmaf(acc[j].x, sc.x, fmaf(bb.x, sc.x, tt.x));
      res.y = fmaf(acc[j].y, sc.y, fmaf(bb.y, sc.y, tt.y));
      res.z = fmaf(acc[j].z, sc.z, fmaf(bb.z, sc.z, tt.z));
      res.w = fmaf(acc[j].w, sc.w, fmaf(bb.w, sc.w, tt.w));
    } else {
      float4 bb = *(const float4*)(cb + co0);
      res.x = acc[j].x + bb.x; res.y = acc[j].y + bb.y;
      res.z = acc[j].z + bb.z; res.w = acc[j].w + bb.w;
    }
    if (RELU) {
      res.x = fmaxf(res.x, 0.f); res.y = fmaxf(res.y, 0.f);
      res.z = fmaxf(res.z, 0.f); res.w = fmaxf(res.w, 0.f);
    }
    float* yp = y + ((size_t)(b * HW + h) * HW + (w0 + j)) * COUT + co0;
    *(float4*)yp = res;
  }
}

// 2x2 max pool, NHWC
template <int C, int HWI>
__global__ void pool_kernel(const float* __restrict__ x, float* __restrict__ y) {
  constexpr int HO = HWI / 2;
  constexpr int C4 = C / 4;
  int f = blockIdx.x * 256 + threadIdx.x;
  int c4 = f % C4; int rest = f / C4;
  int wo = rest % HO; rest /= HO;
  int ho = rest % HO; int b = rest / HO;
  const float* p = x + (((size_t)(b * HWI + 2 * ho) * HWI) + 2 * wo) * C + c4 * 4;
  float4 a = *(const float4*)p;
  float4 b2 = *(const float4*)(p + C);
  float4 c2 = *(const float4*)(p + (size_t)HWI * C);
  float4 d2 = *(const float4*)(p + (size_t)HWI * C + C);
  float4 m;
  m.x = fmaxf(fmaxf(a.x, b2.x), fmaxf(c2.x, d2.x));
  m.y = fmaxf(fmaxf(a.y, b2.y), fmaxf(c2.y, d2.y));
  m.z = fmaxf(fmaxf(a.z, b2.z), fmaxf(c2.z, d2.z));
  m.w = fmaxf(fmaxf(a.w, b2.w), fmaxf(c2.w, d2.w));
  float* yp = y + ((size_t)(b * HO + ho) * HO + wo) * C + c4 * 4;
  *(float4*)yp = m;
}

// 1x1 conv 256 -> 10 + bias (no relu), 16x16 spatial
__global__ void head2_kernel(const float* __restrict__ x, const float* __restrict__ wk,
                             const float* __restrict__ bias, float* __restrict__ y) {
  int h = blockIdx.x, b = blockIdx.y;
  int t = threadIdx.x;
  int co = t & 15, w = t >> 4;
  if (co >= 10) return;
  const float* xr = x + ((size_t)(b * 16 + h) * 16 + w) * 256;
  float acc = 0.f;
#pragma unroll 4
  for (int ci = 0; ci < 256; ci += 4) {
    float4 in4 = *(const float4*)(xr + ci);
    acc = fmaf(in4.x, wk[(ci + 0) * 10 + co], acc);
    acc = fmaf(in4.y, wk[(ci + 1) * 10 + co], acc);
    acc = fmaf(in4.z, wk[(ci + 2) * 10 + co], acc);
    acc = fmaf(in4.w, wk[(ci + 3) * 10 + co], acc);
  }
  y[((size_t)(b * 16 + h) * 16 + w) * 10 + co] = acc + bias[co];
}

// scatter reduced 16x16 head output -> full 27x31 NCHW output
__global__ void scatter_kernel(const float* __restrict__ y, float* __restrict__ out) {
  int idx = blockIdx.x * 256 + threadIdx.x;
  if (idx >= 4 * 10 * 27 * 31) return;
  int c = idx % 31;
  int r = (idx / 31) % 27;
  int ch = (idx / (31 * 27)) % 10;
  int b = idx / (31 * 27 * 10);
  int rr = (r <= 7) ? r : ((r >= 20) ? r - 11 : 7);
  int cc = (c <= 7) ? c : ((c >= 24) ? c - 15 : 7);
  out[idx] = y[((size_t)(b * 16 + rr) * 16 + cc) * 10 + ch];
}

// ---------------------------------------------------------------------------
extern "C" void kernel_launch(void* const* d_in, const int* in_sizes, int n_in,
                              void* d_out, int out_size, void* d_ws, size_t ws_size,
                              hipStream_t stream) {
  (void)in_sizes; (void)n_in; (void)out_size; (void)ws_size;
  const float* pillars = (const float*)d_in[0];
  const float* w1 = (const float*)d_in[1];
  const float* b1 = (const float*)d_in[2];
  const float* s1 = (const float*)d_in[3];
  const float* t1 = (const float*)d_in[4];
  const float* w2 = (const float*)d_in[5];
  const float* b2 = (const float*)d_in[6];
  const float* s2 = (const float*)d_in[7];
  const float* t2 = (const float*)d_in[8];
  const float* ck[6], *cbv[6], *csv[6], *ctv[6];
  for (int i = 0; i < 6; ++i) {
    ck[i]  = (const float*)d_in[9 + i * 4];
    cbv[i] = (const float*)d_in[10 + i * 4];
    csv[i] = (const float*)d_in[11 + i * 4];
    ctv[i] = (const float*)d_in[12 + i * 4];
  }
  const float* hk1 = (const float*)d_in[33];
  const float* hb1 = (const float*)d_in[34];
  const float* hk2 = (const float*)d_in[35];
  const float* hb2 = (const float*)d_in[36];
  const int* num_points = (const int*)d_in[37];
  float* out = (float*)d_out;

  char* ws = (char*)d_ws;
  float* partial        = (float*)(ws + 0);          // 6000*64*4 = 1,536,000
  int*   pcnt           = (int*)(ws + 1540096);      // 24,000
  float* mean           = (float*)(ws + 1568768);    // 1,024
  unsigned short* wfrag = (unsigned short*)(ws + 1572864); // 12,288
  float4* cfrag         = (float4*)(ws + 1589248);   // 4,096
  float* bufA           = (float*)(ws + (2u << 20)); // 4.19 MB
  float* bufB           = (float*)(ws + (7u << 20)); // 4.19 MB

  setup_kernel<<<1, 64, 0, stream>>>(w1, b1, s1, t1, w2, b2, s2, t2, wfrag, cfrag);
  pillar_kernel<<<6000, 256, 0, stream>>>(pillars, num_points, wfrag, cfrag,
                                          partial, pcnt);
  mean_kernel<<<4, 256, 0, stream>>>(partial, pcnt, mean);
  broadcast_kernel<<<1024, 256, 0, stream>>>(mean, bufA);

  conv3x3_kernel<64, 64, 64, 2, true, true><<<dim3(2, 64, 4), 256, 0, stream>>>(
      bufA, ck[0], cbv[0], csv[0], ctv[0], bufB);
  conv3x3_kernel<64, 64, 64, 2, true, true><<<dim3(2, 64, 4), 256, 0, stream>>>(
      bufB, ck[1], cbv[1], csv[1], ctv[1], bufA);
  pool_kernel<64, 64><<<256, 256, 0, stream>>>(bufA, bufB);
  conv3x3_kernel<64, 128, 32, 1, true, true><<<dim3(4, 32, 4), 256, 0, stream>>>(
      bufB, ck[2], cbv[2], csv[2], ctv[2], bufA);
  conv3x3_kernel<128, 128, 32, 1, true, true><<<dim3(4, 32, 4), 256, 0, stream>>>(
      bufA, ck[3], cbv[3], csv[3], ctv[3], bufB);
  pool_kernel<128, 32><<<128, 256, 0, stream>>>(bufB, bufA);
  conv3x3_kernel<128, 256, 16, 1, true, true><<<dim3(4, 16, 4), 256, 0, stream>>>(
      bufA, ck[4], cbv[4], csv[4], ctv[4], bufB);
  conv3x3_kernel<256, 256, 16, 1, true, true><<<dim3(4, 16, 4), 256, 0, stream>>>(
      bufB, ck[5], cbv[5], csv[5], ctv[5], bufA);
  conv3x3_kernel<256, 256, 16, 1, true, false><<<dim3(4, 16, 4), 256, 0, stream>>>(
      bufA, hk1, hb1, nullptr, nullptr, bufB);
  head2_kernel<<<dim3(16, 4), 256, 0, stream>>>(bufB, hk2, hb2, bufA);
  scatter_kernel<<<131, 256, 0, stream>>>(bufA, out);
}

// Round 3
// 895.457 us; speedup vs baseline: 1.1653x; 1.0462x over previous
//
#include <hip/hip_runtime.h>

// ---------- types ----------
typedef __bf16 vbf8 __attribute__((ext_vector_type(8)));
typedef unsigned short us8 __attribute__((ext_vector_type(8)));
typedef float f32x4 __attribute__((ext_vector_type(4)));
typedef float f32x4u __attribute__((ext_vector_type(4), aligned(4)));

// ---------------------------------------------------------------------------
// setup: precompute bf16 MFMA weight fragments + folded BN coeffs per lane.
// wfrag[12][64][8] bf16, cfrag[4][64] float4 (a1,be1,a2,be2).
// ---------------------------------------------------------------------------
__global__ void setup_kernel(const float* __restrict__ w1, const float* __restrict__ b1,
                             const float* __restrict__ s1, const float* __restrict__ t1,
                             const float* __restrict__ w2, const float* __restrict__ b2,
                             const float* __restrict__ s2, const float* __restrict__ t2,
                             __bf16* __restrict__ wfrag, float4* __restrict__ cfrag) {
  int l = threadIdx.x;                       // 0..63
  int s = l & 15, g = l >> 4;
#pragma unroll
  for (int n = 0; n < 4; ++n) {
    int co = s + 16 * n;
#pragma unroll
    for (int e = 0; e < 8; ++e) {
      int k = g * 8 + e;
      wfrag[(n * 64 + l) * 8 + e] = (k < 9) ? (__bf16)w1[k * 64 + co] : (__bf16)0.f;
      wfrag[((4 + n) * 64 + l) * 8 + e] = (__bf16)w2[k * 64 + co];
      wfrag[((8 + n) * 64 + l) * 8 + e] = (__bf16)w2[(32 + k) * 64 + co];
    }
    cfrag[n * 64 + l] = make_float4(s1[co], fmaf(b1[co], s1[co], t1[co]),
                                    s2[co], fmaf(b2[co], s2[co], t2[co]));
  }
}

// ---------------------------------------------------------------------------
// weight transpose+convert: all 7 conv tensors HWIO [tap][ci][co] f32
//   -> wT [tap][co][ci] bf16, concatenated.
// ---------------------------------------------------------------------------
__global__ void convw_kernel(const float* __restrict__ k1, const float* __restrict__ k2,
                             const float* __restrict__ k3, const float* __restrict__ k4,
                             const float* __restrict__ k5, const float* __restrict__ k6,
                             const float* __restrict__ kh, __bf16* __restrict__ wT) {
  int id = blockIdx.x * 256 + threadIdx.x;
  if (id >= 1769472) return;
  const float* src; int CI, CO, base;
  if (id < 36864)        { src = k1; base = 0;       CI = 64;  CO = 64; }
  else if (id < 73728)   { src = k2; base = 36864;   CI = 64;  CO = 64; }
  else if (id < 147456)  { src = k3; base = 73728;   CI = 64;  CO = 128; }
  else if (id < 294912)  { src = k4; base = 147456;  CI = 128; CO = 128; }
  else if (id < 589824)  { src = k5; base = 294912;  CI = 128; CO = 256; }
  else if (id < 1179648) { src = k6; base = 589824;  CI = 256; CO = 256; }
  else                   { src = kh; base = 1179648; CI = 256; CO = 256; }
  int loc = id - base;
  int tap = loc / (CI * CO); int rem = loc % (CI * CO);
  int co = rem / CI; int ci = rem % CI;
  wT[id] = (__bf16)src[(tap * CI + ci) * CO + co];
}

// ---------------------------------------------------------------------------
// Stage A: pillar feature net (bf16 MFMA), masked max, block partial sums.
// 2 pillars per wave; 6000 blocks x 4 waves.
// ---------------------------------------------------------------------------
__global__ __launch_bounds__(256) void pillar_kernel(
    const float* __restrict__ pil, const int* __restrict__ npt,
    const __bf16* __restrict__ wfrag, const float4* __restrict__ cfrag,
    float* __restrict__ partial, int* __restrict__ pcnt)
{
  __shared__ __bf16 ldsa[4][16 * 80];
  __shared__ float redf[4][64];
  __shared__ int redc[4];
  const int tid = threadIdx.x;
  const int wv = tid >> 6, lane = tid & 63;
  const int s = lane & 15, g = lane >> 4;
  __bf16* lds = ldsa[wv];
  const int wid = blockIdx.x * 4 + wv;       // 0..23999
  const int b = wid / 6000;
  const int p0 = (wid - b * 6000) * 2;

  vbf8 w1f[4], w2f0[4], w2f1[4];
  float a1[4], be1[4], a2[4], be2[4];
#pragma unroll
  for (int n = 0; n < 4; ++n) {
    w1f[n]  = *(const vbf8*)(wfrag + ((0 + n) * 64 + lane) * 8);
    w2f0[n] = *(const vbf8*)(wfrag + ((4 + n) * 64 + lane) * 8);
    w2f1[n] = *(const vbf8*)(wfrag + ((8 + n) * 64 + lane) * 8);
    float4 c = cfrag[n * 64 + lane];
    a1[n] = c.x; be1[n] = c.y; a2[n] = c.z; be2[n] = c.w;
  }

  float fsum[4] = {0.f, 0.f, 0.f, 0.f};
  int cnt = 0;

  for (int i = 0; i < 2; ++i) {
    int pidx = b * 12000 + p0 + i;
    int np = npt[pidx];
    if (np <= 0) continue;     // wave-uniform
    ++cnt;
    float feat[4][4];
#pragma unroll
    for (int n = 0; n < 4; ++n)
#pragma unroll
      for (int r = 0; r < 4; ++r) feat[n][r] = 0.f;

    int ngrp = (np + 15) >> 4;
    const float* pbase = pil + (size_t)pidx * 900;
    for (int grp = 0; grp < ngrp; ++grp) {
      // A1 fragment: point row = s, k = g*8+e. Unconditional vector loads.
      int pt = grp * 16 + s; pt = min(pt, 99);
      const float* ptp = pbase + pt * 9;
      f32x4u lo = *(const f32x4u*)ptp;
      f32x4u hi = *(const f32x4u*)(ptp + 4);
      float v8 = ptp[8];
      vbf8 af;
      af[0] = (__bf16)(g == 0 ? lo[0] : (g == 1 ? v8 : 0.f));
      af[1] = (__bf16)(g == 0 ? lo[1] : 0.f);
      af[2] = (__bf16)(g == 0 ? lo[2] : 0.f);
      af[3] = (__bf16)(g == 0 ? lo[3] : 0.f);
      af[4] = (__bf16)(g == 0 ? hi[0] : 0.f);
      af[5] = (__bf16)(g == 0 ? hi[1] : 0.f);
      af[6] = (__bf16)(g == 0 ? hi[2] : 0.f);
      af[7] = (__bf16)(g == 0 ? hi[3] : 0.f);

      const f32x4 z = {0.f, 0.f, 0.f, 0.f};
      f32x4 d1[4];
#pragma unroll
      for (int n = 0; n < 4; ++n)
        d1[n] = __builtin_amdgcn_mfma_f32_16x16x32_bf16(af, w1f[n], z, 0, 0, 0);

      // bn1+relu -> bf16 -> LDS transpose [pt][ch] (stride 80, XOR swizzle)
#pragma unroll
      for (int n = 0; n < 4; ++n)
#pragma unroll
        for (int r = 0; r < 4; ++r) {
          float h = fmaxf(fmaf(d1[n][r], a1[n], be1[n]), 0.f);
          int pt2 = g * 4 + r;
          int ch = (s + 16 * n) ^ ((pt2 >> 2) << 3);
          lds[pt2 * 80 + ch] = (__bf16)h;
        }
      __builtin_amdgcn_wave_barrier();

      // A2 fragments: pt = s, ch = kt*32 + g*8 + e
      vbf8 a2f0 = *(const vbf8*)(lds + s * 80 + ((g * 8) ^ ((s >> 2) << 3)));
      vbf8 a2f1 = *(const vbf8*)(lds + s * 80 + ((32 + g * 8) ^ ((s >> 2) << 3)));
      f32x4 d2[4];
#pragma unroll
      for (int n = 0; n < 4; ++n) {
        d2[n] = __builtin_amdgcn_mfma_f32_16x16x32_bf16(a2f0, w2f0[n], z, 0, 0, 0);
        d2[n] = __builtin_amdgcn_mfma_f32_16x16x32_bf16(a2f1, w2f1[n], d2[n], 0, 0, 0);
      }
      // bn2+relu, masked max
#pragma unroll
      for (int n = 0; n < 4; ++n)
#pragma unroll
        for (int r = 0; r < 4; ++r) {
          float h = fmaxf(fmaf(d2[n][r], a2[n], be2[n]), 0.f);
          if (grp * 16 + g * 4 + r < np) feat[n][r] = fmaxf(feat[n][r], h);
        }
    }
#pragma unroll
    for (int n = 0; n < 4; ++n) {
      float m = fmaxf(fmaxf(feat[n][0], feat[n][1]), fmaxf(feat[n][2], feat[n][3]));
      m = fmaxf(m, __shfl_xor(m, 16));
      m = fmaxf(m, __shfl_xor(m, 32));
      fsum[n] += m;
    }
  }
  if (g == 0) {
#pragma unroll
    for (int n = 0; n < 4; ++n) redf[wv][s + 16 * n] = fsum[n];
  }
  if (lane == 0) redc[wv] = cnt;
  __syncthreads();
  if (tid < 64) {
    float tot = redf[0][tid] + redf[1][tid] + redf[2][tid] + redf[3][tid];
    partial[blockIdx.x * 64 + tid] = tot;
    if (tid == 0) pcnt[blockIdx.x] = redc[0] + redc[1] + redc[2] + redc[3];
  }
}

// finish the mean: 4 blocks (one per batch), 1500 partial blocks each
__global__ void mean_kernel(const float* __restrict__ partial,
                            const int* __restrict__ pcnt,
                            float* __restrict__ mean) {
  int b = blockIdx.x, t = threadIdx.x;
  int c = t & 63, q = t >> 6;
  float sum = 0.f;
  for (int w = q; w < 1500; w += 4) sum += partial[(b * 1500 + w) * 64 + c];
  int cl = 0;
  for (int w = t; w < 1500; w += 256) cl += pcnt[b * 1500 + w];
  __shared__ float sh[256];
  __shared__ int shc[256];
  sh[t] = sum; shc[t] = cl;
  __syncthreads();
  for (int o = 128; o > 0; o >>= 1) {
    if (t < o) shc[t] += shc[t + o];
    __syncthreads();
  }
  if (t < 64) {
    float tot = sh[t] + sh[t + 64] + sh[t + 128] + sh[t + 192];
    mean[b * 64 + t] = tot / (float)(shc[0] > 0 ? shc[0] : 1);
  }
}

// zero the 1-px border of a padded [4][H2][H2][C] bf16 buffer
template <int H2, int C>
__global__ void zero_border_kernel(__bf16* __restrict__ x) {
  int idx = blockIdx.x * 256 + threadIdx.x;
  if (idx >= 4 * H2 * H2) return;
  int w = idx % H2; int rest = idx / H2; int h = rest % H2;
  if (h != 0 && h != H2 - 1 && w != 0 && w != H2 - 1) return;
  us8 zz = {0, 0, 0, 0, 0, 0, 0, 0};
  __bf16* p = x + (size_t)idx * C;
#pragma unroll
  for (int c = 0; c < C; c += 8) *(us8*)(p + c) = zz;
}

// broadcast mean -> x0 interior of [4][66][66][64] bf16 padded
__global__ void broadcast_kernel(const float* __restrict__ mean,
                                 __bf16* __restrict__ x0) {
  int idx = blockIdx.x * 256 + threadIdx.x;   // 4*64*64*8 = 131072
  int c8 = idx & 7; int rest = idx >> 3;
  int w = rest & 63; rest >>= 6;
  int h = rest & 63; int b = rest >> 6;
  const float* mb = mean + b * 64 + c8 * 8;
  vbf8 v;
#pragma unroll
  for (int e = 0; e < 8; ++e) v[e] = (__bf16)mb[e];
  *(vbf8*)(x0 + (((size_t)(b * 66 + h + 1) * 66) + (w + 1)) * 64 + c8 * 8) = v;
}

// ---------------------------------------------------------------------------
// bf16 MFMA implicit-GEMM 3x3 SAME conv over padded NHWC bf16.
// Block = 4 waves; each wave: M=32 raster rows x N=COUT. K = 9 taps * CIN.
// A-frag: row = lane&15, k = (lane>>4)*8+e (16B global loads from x_pad)
// B-frag: k = (lane>>4)*8+e, n = lane&15 (16B loads from wT [tap][co][ci])
// D: n = lane&15, m-row = 4*(lane>>4)+r.
// ---------------------------------------------------------------------------
template <int CIN, int COUT, int HW, bool HAS_BN, bool OUT_F32>
__global__ __launch_bounds__(256) void mconv_kernel(
    const __bf16* __restrict__ x, const __bf16* __restrict__ wt,
    const float* __restrict__ cb, const float* __restrict__ cs,
    const float* __restrict__ ct, __bf16* __restrict__ ypad,
    float* __restrict__ yf32)
{
  constexpr int H2 = HW + 2;
  constexpr int NF = COUT / 16;
  constexpr int KC = CIN / 32;
  constexpr int LOG = (HW == 64) ? 6 : (HW == 32) ? 5 : 4;
  const int tid = threadIdx.x, wv = tid >> 6, lane = tid & 63;
  const int s = lane & 15, g = lane >> 4;
  const int m0 = blockIdx.x * 128 + wv * 32;
  const int b = m0 >> (2 * LOG);
  const int mb = m0 - (b << (2 * LOG));

  size_t arow[2];
#pragma unroll
  for (int mf = 0; mf < 2; ++mf) {
    int m = mb + mf * 16 + s;
    int hh = m >> LOG, ww = m & (HW - 1);
    arow[mf] = ((size_t)(b * H2 + hh) * H2 + ww) * CIN;
  }

  f32x4 acc[2][NF];
#pragma unroll
  for (int mf = 0; mf < 2; ++mf)
#pragma unroll
    for (int nf = 0; nf < NF; ++nf) acc[mf][nf] = (f32x4){0.f, 0.f, 0.f, 0.f};

#pragma unroll
  for (int dh = 0; dh < 3; ++dh)
#pragma unroll
    for (int dw = 0; dw < 3; ++dw) {
      const size_t aoff = ((size_t)dh * H2 + dw) * CIN + 8 * g;
      const __bf16* wtap = wt + (size_t)(dh * 3 + dw) * COUT * CIN + 8 * g;
      for (int ck = 0; ck < KC; ++ck) {
        vbf8 a0 = *(const vbf8*)(x + arow[0] + aoff + ck * 32);
        vbf8 a1 = *(const vbf8*)(x + arow[1] + aoff + ck * 32);
#pragma unroll
        for (int nf = 0; nf < NF; ++nf) {
          vbf8 bb = *(const vbf8*)(wtap + (size_t)(nf * 16 + s) * CIN + ck * 32);
          acc[0][nf] = __builtin_amdgcn_mfma_f32_16x16x32_bf16(a0, bb, acc[0][nf], 0, 0, 0);
          acc[1][nf] = __builtin_amdgcn_mfma_f32_16x16x32_bf16(a1, bb, acc[1][nf], 0, 0, 0);
        }
      }
    }

#pragma unroll
  for (int nf = 0; nf < NF; ++nf) {
    int co = nf * 16 + s;
    float sc, sh;
    if (HAS_BN) { sc = cs[co]; sh = fmaf(cb[co], sc, ct[co]); }
    else        { sc = 1.f;    sh = cb[co]; }
#pragma unroll
    for (int mf = 0; mf < 2; ++mf)
#pragma unroll
      for (int r = 0; r < 4; ++r) {
        int m = mb + mf * 16 + 4 * g + r;
        int hh = m >> LOG, ww = m & (HW - 1);
        float v = fmaxf(fmaf(acc[mf][nf][r], sc, sh), 0.f);
        if constexpr (OUT_F32)
          yf32[((size_t)(b * HW + hh) * HW + ww) * COUT + co] = v;
        else
          ypad[((size_t)(b * H2 + hh + 1) * H2 + (ww + 1)) * COUT + co] = (__bf16)v;
      }
  }
}

// 2x2 max pool bf16 padded -> bf16 padded (writes its own zero borders).
// u16 max valid: inputs are post-ReLU (non-negative bf16).
template <int C, int HI>
__global__ void pool_kernel(const __bf16* __restrict__ x, __bf16* __restrict__ y) {
  constexpr int HO = HI / 2, W2I = HI + 2, W2O = HO + 2, C8 = C / 8;
  int idx = blockIdx.x * 256 + threadIdx.x;
  if (idx >= 4 * W2O * W2O * C8) return;
  int c8 = idx % C8; int rest = idx / C8;
  int wo = rest % W2O; rest /= W2O;
  int ho = rest % W2O; int b = rest / W2O;
  us8 out;
  if (ho == 0 || ho == W2O - 1 || wo == 0 || wo == W2O - 1) {
    out = (us8){0, 0, 0, 0, 0, 0, 0, 0};
  } else {
    int hi = 2 * (ho - 1) + 1, wi = 2 * (wo - 1) + 1;
    const unsigned short* p =
        (const unsigned short*)x + (((size_t)(b * W2I + hi) * W2I) + wi) * C + c8 * 8;
    us8 v0 = *(const us8*)p;
    us8 v1 = *(const us8*)(p + C);
    us8 v2 = *(const us8*)(p + (size_t)W2I * C);
    us8 v3 = *(const us8*)(p + (size_t)W2I * C + C);
#pragma unroll
    for (int e = 0; e < 8; ++e) {
      unsigned short a = v0[e] > v1[e] ? v0[e] : v1[e];
      unsigned short c = v2[e] > v3[e] ? v2[e] : v3[e];
      out[e] = a > c ? a : c;
    }
  }
  *(us8*)((unsigned short*)y + (((size_t)(b * W2O + ho) * W2O) + wo) * C + c8 * 8) = out;
}

// 1x1 conv 256 -> 10 + bias (no relu), 16x16 spatial, fp32
__global__ void head2_kernel(const float* __restrict__ x, const float* __restrict__ wk,
                             const float* __restrict__ bias, float* __restrict__ y) {
  int h = blockIdx.x, b = blockIdx.y;
  int t = threadIdx.x;
  int co = t & 15, w = t >> 4;
  if (co >= 10) return;
  const float* xr = x + ((size_t)(b * 16 + h) * 16 + w) * 256;
  float acc = 0.f;
#pragma unroll 4
  for (int ci = 0; ci < 256; ci += 4) {
    float4 in4 = *(const float4*)(xr + ci);
    acc = fmaf(in4.x, wk[(ci + 0) * 10 + co], acc);
    acc = fmaf(in4.y, wk[(ci + 1) * 10 + co], acc);
    acc = fmaf(in4.z, wk[(ci + 2) * 10 + co], acc);
    acc = fmaf(in4.w, wk[(ci + 3) * 10 + co], acc);
  }
  y[((size_t)(b * 16 + h) * 16 + w) * 10 + co] = acc + bias[co];
}

// scatter reduced 16x16 head output -> full 27x31 NCHW output
__global__ void scatter_kernel(const float* __restrict__ y, float* __restrict__ out) {
  int idx = blockIdx.x * 256 + threadIdx.x;
  if (idx >= 4 * 10 * 27 * 31) return;
  int c = idx % 31;
  int r = (idx / 31) % 27;
  int ch = (idx / (31 * 27)) % 10;
  int b = idx / (31 * 27 * 10);
  int rr = (r <= 7) ? r : ((r >= 20) ? r - 11 : 7);
  int cc = (c <= 7) ? c : ((c >= 24) ? c - 15 : 7);
  out[idx] = y[((size_t)(b * 16 + rr) * 16 + cc) * 10 + ch];
}

// ---------------------------------------------------------------------------
extern "C" void kernel_launch(void* const* d_in, const int* in_sizes, int n_in,
                              void* d_out, int out_size, void* d_ws, size_t ws_size,
                              hipStream_t stream) {
  (void)in_sizes; (void)n_in; (void)out_size; (void)ws_size;
  const float* pillars = (const float*)d_in[0];
  const float* w1 = (const float*)d_in[1];
  const float* b1 = (const float*)d_in[2];
  const float* s1 = (const float*)d_in[3];
  const float* t1 = (const float*)d_in[4];
  const float* w2 = (const float*)d_in[5];
  const float* b2 = (const float*)d_in[6];
  const float* s2 = (const float*)d_in[7];
  const float* t2 = (const float*)d_in[8];
  const float* ck[6], *cbv[6], *csv[6], *ctv[6];
  for (int i = 0; i < 6; ++i) {
    ck[i]  = (const float*)d_in[9 + i * 4];
    cbv[i] = (const float*)d_in[10 + i * 4];
    csv[i] = (const float*)d_in[11 + i * 4];
    ctv[i] = (const float*)d_in[12 + i * 4];
  }
  const float* hk1 = (const float*)d_in[33];
  const float* hb1 = (const float*)d_in[34];
  const float* hk2 = (const float*)d_in[35];
  const float* hb2 = (const float*)d_in[36];
  const int* num_points = (const int*)d_in[37];
  float* out = (float*)d_out;

  char* ws = (char*)d_ws;
  float*  partial  = (float*)(ws + 0);             // 1,536,000 B (reused as h1out)
  float*  h1out    = (float*)(ws + 0);             // 1,048,576 B
  int*    pcnt     = (int*)(ws + 1572864);         // 24,000 B
  float*  mean     = (float*)(ws + 1605632);       // 1,024 B
  __bf16* wfrag    = (__bf16*)(ws + 1609728);      // 12,288 B
  float4* cfrag    = (float4*)(ws + 1622016);      // 4,096 B
  float*  h2out    = (float*)(ws + 1630208);       // 40,960 B
  __bf16* wT       = (__bf16*)(ws + 1835008);      // 3,538,944 B
  __bf16* bufA     = (__bf16*)(ws + 5767168);      // <= 2,230,272 B
  __bf16* bufB     = (__bf16*)(ws + 8912896);      // <= 2,230,272 B

  // wT per-conv element offsets
  __bf16* wt1 = wT + 0;       __bf16* wt2 = wT + 36864;
  __bf16* wt3 = wT + 73728;   __bf16* wt4 = wT + 147456;
  __bf16* wt5 = wT + 294912;  __bf16* wt6 = wT + 589824;
  __bf16* wth = wT + 1179648;

  setup_kernel<<<1, 64, 0, stream>>>(w1, b1, s1, t1, w2, b2, s2, t2, wfrag, cfrag);
  convw_kernel<<<6912, 256, 0, stream>>>(ck[0], ck[1], ck[2], ck[3], ck[4], ck[5],
                                         hk1, wT);
  zero_border_kernel<66, 64><<<69, 256, 0, stream>>>(bufA);
  zero_border_kernel<66, 64><<<69, 256, 0, stream>>>(bufB);

  pillar_kernel<<<6000, 256, 0, stream>>>(pillars, num_points, wfrag, cfrag,
                                          partial, pcnt);
  mean_kernel<<<4, 256, 0, stream>>>(partial, pcnt, mean);
  broadcast_kernel<<<512, 256, 0, stream>>>(mean, bufA);

  // backbone (ping-pong A/B)
  mconv_kernel<64, 64, 64, true, false><<<128, 256, 0, stream>>>(
      bufA, wt1, cbv[0], csv[0], ctv[0], bufB, nullptr);
  mconv_kernel<64, 64, 64, true, false><<<128, 256, 0, stream>>>(
      bufB, wt2, cbv[1], csv[1], ctv[1], bufA, nullptr);
  pool_kernel<64, 64><<<145, 256, 0, stream>>>(bufA, bufB);       // -> [34][34][64]
  zero_border_kernel<34, 128><<<19, 256, 0, stream>>>(bufA);      // c3-out borders
  mconv_kernel<64, 128, 32, true, false><<<32, 256, 0, stream>>>(
      bufB, wt3, cbv[2], csv[2], ctv[2], bufA, nullptr);
  mconv_kernel<128, 128, 32, true, false><<<32, 256, 0, stream>>>(
      bufA, wt4, cbv[3], csv[3], ctv[3], bufB, nullptr);
  pool_kernel<128, 32><<<81, 256, 0, stream>>>(bufB, bufA);       // -> [18][18][128]
  zero_border_kernel<18, 256><<<6, 256, 0, stream>>>(bufB);       // c5-out borders
  mconv_kernel<128, 256, 16, true, false><<<8, 256, 0, stream>>>(
      bufA, wt5, cbv[4], csv[4], ctv[4], bufB, nullptr);
  zero_border_kernel<18, 256><<<6, 256, 0, stream>>>(bufA);       // c6-out borders
  mconv_kernel<256, 256, 16, true, false><<<8, 256, 0, stream>>>(
      bufB, wt6, cbv[5], csv[5], ctv[5], bufA, nullptr);
  mconv_kernel<256, 256, 16, false, true><<<8, 256, 0, stream>>>(
      bufA, wth, hb1, nullptr, nullptr, nullptr, h1out);

  head2_kernel<<<dim3(16, 4), 256, 0, stream>>>(h1out, hk2, hb2, h2out);
  scatter_kernel<<<131, 256, 0, stream>>>(h2out, out);
}

// Round 4
// 372.350 us; speedup vs baseline: 2.8024x; 2.4049x over previous
//
#include <hip/hip_runtime.h>

// ---------- types ----------
typedef __bf16 vbf8 __attribute__((ext_vector_type(8)));
typedef __bf16 vbf4 __attribute__((ext_vector_type(4)));
typedef unsigned short us8 __attribute__((ext_vector_type(8)));
typedef float f32x4 __attribute__((ext_vector_type(4)));
typedef float f32x4u __attribute__((ext_vector_type(4), aligned(4)));

// ---------------------------------------------------------------------------
// setup: precompute bf16 MFMA weight fragments + folded BN coeffs per lane.
// ---------------------------------------------------------------------------
__global__ void setup_kernel(const float* __restrict__ w1, const float* __restrict__ b1,
                             const float* __restrict__ s1, const float* __restrict__ t1,
                             const float* __restrict__ w2, const float* __restrict__ b2,
                             const float* __restrict__ s2, const float* __restrict__ t2,
                             __bf16* __restrict__ wfrag, float4* __restrict__ cfrag) {
  int l = threadIdx.x;                       // 0..63
  int s = l & 15, g = l >> 4;
#pragma unroll
  for (int n = 0; n < 4; ++n) {
    int co = s + 16 * n;
#pragma unroll
    for (int e = 0; e < 8; ++e) {
      int k = g * 8 + e;
      wfrag[(n * 64 + l) * 8 + e] = (k < 9) ? (__bf16)w1[k * 64 + co] : (__bf16)0.f;
      wfrag[((4 + n) * 64 + l) * 8 + e] = (__bf16)w2[k * 64 + co];
      wfrag[((8 + n) * 64 + l) * 8 + e] = (__bf16)w2[(32 + k) * 64 + co];
    }
    cfrag[n * 64 + l] = make_float4(s1[co], fmaf(b1[co], s1[co], t1[co]),
                                    s2[co], fmaf(b2[co], s2[co], t2[co]));
  }
}

// ---------------------------------------------------------------------------
// weight transpose+convert: HWIO [tap][ci][co] f32 -> wT [tap][co][ci] bf16.
// ---------------------------------------------------------------------------
__global__ void convw_kernel(const float* __restrict__ k1, const float* __restrict__ k2,
                             const float* __restrict__ k3, const float* __restrict__ k4,
                             const float* __restrict__ k5, const float* __restrict__ k6,
                             const float* __restrict__ kh, __bf16* __restrict__ wT) {
  int id = blockIdx.x * 256 + threadIdx.x;
  if (id >= 1769472) return;
  const float* src; int CI, CO, base;
  if (id < 36864)        { src = k1; base = 0;       CI = 64;  CO = 64; }
  else if (id < 73728)   { src = k2; base = 36864;   CI = 64;  CO = 64; }
  else if (id < 147456)  { src = k3; base = 73728;   CI = 64;  CO = 128; }
  else if (id < 294912)  { src = k4; base = 147456;  CI = 128; CO = 128; }
  else if (id < 589824)  { src = k5; base = 294912;  CI = 128; CO = 256; }
  else if (id < 1179648) { src = k6; base = 589824;  CI = 256; CO = 256; }
  else                   { src = kh; base = 1179648; CI = 256; CO = 256; }
  int loc = id - base;
  int tap = loc / (CI * CO); int rem = loc % (CI * CO);
  int co = rem / CI; int ci = rem % CI;
  wT[id] = (__bf16)src[(tap * CI + ci) * CO + co];
}

// ---------------------------------------------------------------------------
// zero the 1-px borders of all padded activation buffers (fused, one launch)
// regions: A64,B64 [4][66][66][64]; C128A,C128B [4][34][34][128];
//          C256A,C256B [4][18][18][256]
// ---------------------------------------------------------------------------
__global__ void zero_borders_kernel(__bf16* __restrict__ a64, __bf16* __restrict__ b64,
                                    __bf16* __restrict__ c128a, __bf16* __restrict__ c128b,
                                    __bf16* __restrict__ c256a, __bf16* __restrict__ c256b) {
  int idx = blockIdx.x * 256 + threadIdx.x;
  __bf16* buf; int H2, C, p;
  if (idx < 34848)       { buf = (idx < 17424) ? a64 : b64;     H2 = 66; C = 64;  p = idx % 17424; }
  else if (idx < 44096)  { int q = idx - 34848; buf = (q < 4624) ? c128a : c128b; H2 = 34; C = 128; p = q % 4624; }
  else if (idx < 46688)  { int q = idx - 44096; buf = (q < 1296) ? c256a : c256b; H2 = 18; C = 256; p = q % 1296; }
  else return;
  int w = p % H2; int h = (p / H2) % H2;
  if (h != 0 && h != H2 - 1 && w != 0 && w != H2 - 1) return;
  us8 zz = {0, 0, 0, 0, 0, 0, 0, 0};
  __bf16* q = buf + (size_t)p * C;
  for (int c = 0; c < C; c += 8) *(us8*)(q + c) = zz;
}

// ---------------------------------------------------------------------------
// Stage A: pillar feature net (bf16 MFMA), masked max, block partial sums.
// ---------------------------------------------------------------------------
__global__ __launch_bounds__(256) void pillar_kernel(
    const float* __restrict__ pil, const int* __restrict__ npt,
    const __bf16* __restrict__ wfrag, const float4* __restrict__ cfrag,
    float* __restrict__ partial, int* __restrict__ pcnt)
{
  __shared__ __bf16 ldsa[4][16 * 80];
  __shared__ float redf[4][64];
  __shared__ int redc[4];
  const int tid = threadIdx.x;
  const int wv = tid >> 6, lane = tid & 63;
  const int s = lane & 15, g = lane >> 4;
  __bf16* lds = ldsa[wv];
  const int wid = blockIdx.x * 4 + wv;       // 0..23999
  const int b = wid / 6000;
  const int p0 = (wid - b * 6000) * 2;

  vbf8 w1f[4], w2f0[4], w2f1[4];
  float a1[4], be1[4], a2[4], be2[4];
#pragma unroll
  for (int n = 0; n < 4; ++n) {
    w1f[n]  = *(const vbf8*)(wfrag + ((0 + n) * 64 + lane) * 8);
    w2f0[n] = *(const vbf8*)(wfrag + ((4 + n) * 64 + lane) * 8);
    w2f1[n] = *(const vbf8*)(wfrag + ((8 + n) * 64 + lane) * 8);
    float4 c = cfrag[n * 64 + lane];
    a1[n] = c.x; be1[n] = c.y; a2[n] = c.z; be2[n] = c.w;
  }

  float fsum[4] = {0.f, 0.f, 0.f, 0.f};
  int cnt = 0;

  for (int i = 0; i < 2; ++i) {
    int pidx = b * 12000 + p0 + i;
    int np = npt[pidx];
    if (np <= 0) continue;     // wave-uniform
    ++cnt;
    float feat[4][4];
#pragma unroll
    for (int n = 0; n < 4; ++n)
#pragma unroll
      for (int r = 0; r < 4; ++r) feat[n][r] = 0.f;

    int ngrp = (np + 15) >> 4;
    const float* pbase = pil + (size_t)pidx * 900;
    for (int grp = 0; grp < ngrp; ++grp) {
      int pt = grp * 16 + s; pt = min(pt, 99);
      const float* ptp = pbase + pt * 9;
      f32x4u lo = *(const f32x4u*)ptp;
      f32x4u hi = *(const f32x4u*)(ptp + 4);
      float v8 = ptp[8];
      vbf8 af;
      af[0] = (__bf16)(g == 0 ? lo[0] : (g == 1 ? v8 : 0.f));
      af[1] = (__bf16)(g == 0 ? lo[1] : 0.f);
      af[2] = (__bf16)(g == 0 ? lo[2] : 0.f);
      af[3] = (__bf16)(g == 0 ? lo[3] : 0.f);
      af[4] = (__bf16)(g == 0 ? hi[0] : 0.f);
      af[5] = (__bf16)(g == 0 ? hi[1] : 0.f);
      af[6] = (__bf16)(g == 0 ? hi[2] : 0.f);
      af[7] = (__bf16)(g == 0 ? hi[3] : 0.f);

      const f32x4 z = {0.f, 0.f, 0.f, 0.f};
      f32x4 d1[4];
#pragma unroll
      for (int n = 0; n < 4; ++n)
        d1[n] = __builtin_amdgcn_mfma_f32_16x16x32_bf16(af, w1f[n], z, 0, 0, 0);

#pragma unroll
      for (int n = 0; n < 4; ++n)
#pragma unroll
        for (int r = 0; r < 4; ++r) {
          float h = fmaxf(fmaf(d1[n][r], a1[n], be1[n]), 0.f);
          int pt2 = g * 4 + r;
          int ch = (s + 16 * n) ^ ((pt2 >> 2) << 3);
          lds[pt2 * 80 + ch] = (__bf16)h;
        }
      __builtin_amdgcn_wave_barrier();

      vbf8 a2f0 = *(const vbf8*)(lds + s * 80 + ((g * 8) ^ ((s >> 2) << 3)));
      vbf8 a2f1 = *(const vbf8*)(lds + s * 80 + ((32 + g * 8) ^ ((s >> 2) << 3)));
      f32x4 d2[4];
#pragma unroll
      for (int n = 0; n < 4; ++n) {
        d2[n] = __builtin_amdgcn_mfma_f32_16x16x32_bf16(a2f0, w2f0[n], z, 0, 0, 0);
        d2[n] = __builtin_amdgcn_mfma_f32_16x16x32_bf16(a2f1, w2f1[n], d2[n], 0, 0, 0);
      }
#pragma unroll
      for (int n = 0; n < 4; ++n)
#pragma unroll
        for (int r = 0; r < 4; ++r) {
          float h = fmaxf(fmaf(d2[n][r], a2[n], be2[n]), 0.f);
          if (grp * 16 + g * 4 + r < np) feat[n][r] = fmaxf(feat[n][r], h);
        }
    }
#pragma unroll
    for (int n = 0; n < 4; ++n) {
      float m = fmaxf(fmaxf(feat[n][0], feat[n][1]), fmaxf(feat[n][2], feat[n][3]));
      m = fmaxf(m, __shfl_xor(m, 16));
      m = fmaxf(m, __shfl_xor(m, 32));
      fsum[n] += m;
    }
  }
  if (g == 0) {
#pragma unroll
    for (int n = 0; n < 4; ++n) redf[wv][s + 16 * n] = fsum[n];
  }
  if (lane == 0) redc[wv] = cnt;
  __syncthreads();
  if (tid < 64) {
    float tot = redf[0][tid] + redf[1][tid] + redf[2][tid] + redf[3][tid];
    partial[blockIdx.x * 64 + tid] = tot;
    if (tid == 0) pcnt[blockIdx.x] = redc[0] + redc[1] + redc[2] + redc[3];
  }
}

// finish the mean: 4 blocks (one per batch), 1500 partial blocks each
__global__ void mean_kernel(const float* __restrict__ partial,
                            const int* __restrict__ pcnt,
                            float* __restrict__ mean) {
  int b = blockIdx.x, t = threadIdx.x;
  int c = t & 63, q = t >> 6;
  float sum = 0.f;
  for (int w = q; w < 1500; w += 4) sum += partial[(b * 1500 + w) * 64 + c];
  int cl = 0;
  for (int w = t; w < 1500; w += 256) cl += pcnt[b * 1500 + w];
  __shared__ float sh[256];
  __shared__ int shc[256];
  sh[t] = sum; shc[t] = cl;
  __syncthreads();
  for (int o = 128; o > 0; o >>= 1) {
    if (t < o) shc[t] += shc[t + o];
    __syncthreads();
  }
  if (t < 64) {
    float tot = sh[t] + sh[t + 64] + sh[t + 128] + sh[t + 192];
    mean[b * 64 + t] = tot / (float)(shc[0] > 0 ? shc[0] : 1);
  }
}

// broadcast mean -> x0 interior of [4][66][66][64] bf16 padded
__global__ void broadcast_kernel(const float* __restrict__ mean,
                                 __bf16* __restrict__ x0) {
  int idx = blockIdx.x * 256 + threadIdx.x;   // 131072
  int c8 = idx & 7; int rest = idx >> 3;
  int w = rest & 63; rest >>= 6;
  int h = rest & 63; int b = rest >> 6;
  const float* mb = mean + b * 64 + c8 * 8;
  vbf8 v;
#pragma unroll
  for (int e = 0; e < 8; ++e) v[e] = (__bf16)mb[e];
  *(vbf8*)(x0 + (((size_t)(b * 66 + h + 1) * 66) + (w + 1)) * 64 + c8 * 8) = v;
}

// ---------------------------------------------------------------------------
// K-split implicit-GEMM 3x3 conv, bf16 MFMA, fp32 partials (no epilogue).
// wave-task = ((mt * NT + nt) * 3 + kg); wave tile = M 32 x N 64, taps {3kg..3kg+2}
// kpart layout: [kg][m][co] fp32
// ---------------------------------------------------------------------------
template <int CIN, int COUT, int HW>
__global__ __launch_bounds__(256) void kconv_kernel(
    const __bf16* __restrict__ x, const __bf16* __restrict__ wt,
    float* __restrict__ kpart)
{
  constexpr int H2 = HW + 2;
  constexpr int NT = COUT / 64;
  constexpr int KC = CIN / 32;
  constexpr int MTOT = 4 * HW * HW;
  constexpr int LOG = (HW == 64) ? 6 : (HW == 32) ? 5 : 4;
  const int tid = threadIdx.x, wv = tid >> 6, lane = tid & 63;
  const int s = lane & 15, g = lane >> 4;
  const int task = blockIdx.x * 4 + wv;
  const int kg = task % 3;
  const int t2 = task / 3;
  const int nt = t2 % NT;
  const int mt = t2 / NT;
  const int m0 = mt * 32;
  const int b = m0 >> (2 * LOG);
  const int mb = m0 - (b << (2 * LOG));

  size_t arow[2];
#pragma unroll
  for (int mf = 0; mf < 2; ++mf) {
    int m = mb + mf * 16 + s;
    int hh = m >> LOG, ww = m & (HW - 1);
    arow[mf] = ((size_t)(b * H2 + hh) * H2 + ww) * CIN;
  }

  f32x4 acc[2][4];
#pragma unroll
  for (int mf = 0; mf < 2; ++mf)
#pragma unroll
    for (int nf = 0; nf < 4; ++nf) acc[mf][nf] = (f32x4){0.f, 0.f, 0.f, 0.f};

#pragma unroll
  for (int j = 0; j < 3; ++j) {
    const int tap = kg * 3 + j;
    const int dh = tap / 3, dw = tap % 3;
    const size_t aoff = ((size_t)dh * H2 + dw) * CIN + 8 * g;
    const __bf16* wtap = wt + ((size_t)tap * COUT + nt * 64) * CIN + 8 * g;
#pragma unroll 2
    for (int ck = 0; ck < KC; ++ck) {
      vbf8 a0 = *(const vbf8*)(x + arow[0] + aoff + ck * 32);
      vbf8 a1 = *(const vbf8*)(x + arow[1] + aoff + ck * 32);
#pragma unroll
      for (int nf = 0; nf < 4; ++nf) {
        vbf8 bb = *(const vbf8*)(wtap + (size_t)(nf * 16 + s) * CIN + ck * 32);
        acc[0][nf] = __builtin_amdgcn_mfma_f32_16x16x32_bf16(a0, bb, acc[0][nf], 0, 0, 0);
        acc[1][nf] = __builtin_amdgcn_mfma_f32_16x16x32_bf16(a1, bb, acc[1][nf], 0, 0, 0);
      }
    }
  }

  float* kp = kpart + (size_t)kg * MTOT * COUT;
#pragma unroll
  for (int mf = 0; mf < 2; ++mf)
#pragma unroll
    for (int nf = 0; nf < 4; ++nf) {
      int co = nt * 64 + nf * 16 + s;
#pragma unroll
      for (int r = 0; r < 4; ++r) {
        int m = m0 + mf * 16 + 4 * g + r;
        kp[(size_t)m * COUT + co] = acc[mf][nf][r];
      }
    }
}

// ---------------------------------------------------------------------------
// reduce K-split partials + BN/bias + ReLU -> padded bf16 (or flat f32)
// ---------------------------------------------------------------------------
template <int COUT, int HW, bool HAS_BN, bool OUT_F32>
__global__ __launch_bounds__(256) void reduce_kernel(
    const float* __restrict__ kpart, const float* __restrict__ cb,
    const float* __restrict__ cs, const float* __restrict__ ct,
    __bf16* __restrict__ ypad, float* __restrict__ yf32)
{
  constexpr int H2 = HW + 2;
  constexpr int MTOT = 4 * HW * HW;
  constexpr int CQ = COUT / 4;
  constexpr int LOG = (HW == 64) ? 6 : (HW == 32) ? 5 : 4;
  int idx = blockIdx.x * 256 + threadIdx.x;
  int cq = idx % CQ; int m = idx / CQ;
  int co0 = cq * 4;
  const f32x4* f4 = (const f32x4*)kpart;
  f32x4 v = f4[(size_t)m * CQ + cq];
  f32x4 v1 = f4[((size_t)MTOT + m) * CQ + cq];
  f32x4 v2 = f4[((size_t)2 * MTOT + m) * CQ + cq];
  v += v1 + v2;
  f32x4 r;
  if (HAS_BN) {
    f32x4 sc = *(const f32x4*)(cs + co0);
    f32x4 bb = *(const f32x4*)(cb + co0);
    f32x4 tt = *(const f32x4*)(ct + co0);
#pragma unroll
    for (int e = 0; e < 4; ++e) r[e] = fmaxf(fmaf(v[e], sc[e], fmaf(bb[e], sc[e], tt[e])), 0.f);
  } else {
    f32x4 bb = *(const f32x4*)(cb + co0);
#pragma unroll
    for (int e = 0; e < 4; ++e) r[e] = fmaxf(v[e] + bb[e], 0.f);
  }
  if constexpr (OUT_F32) {
    *(f32x4*)(yf32 + (size_t)m * COUT + co0) = r;
  } else {
    int b = m >> (2 * LOG);
    int mm = m - (b << (2 * LOG));
    int hh = mm >> LOG, ww = mm & (HW - 1);
    vbf4 o;
#pragma unroll
    for (int e = 0; e < 4; ++e) o[e] = (__bf16)r[e];
    *(vbf4*)(ypad + (((size_t)(b * H2 + hh + 1) * H2) + ww + 1) * COUT + co0) = o;
  }
}

// 2x2 max pool bf16 padded -> bf16 padded (writes its own zero borders).
template <int C, int HI>
__global__ void pool_kernel(const __bf16* __restrict__ x, __bf16* __restrict__ y) {
  constexpr int HO = HI / 2, W2I = HI + 2, W2O = HO + 2, C8 = C / 8;
  int idx = blockIdx.x * 256 + threadIdx.x;
  if (idx >= 4 * W2O * W2O * C8) return;
  int c8 = idx % C8; int rest = idx / C8;
  int wo = rest % W2O; rest /= W2O;
  int ho = rest % W2O; int b = rest / W2O;
  us8 out;
  if (ho == 0 || ho == W2O - 1 || wo == 0 || wo == W2O - 1) {
    out = (us8){0, 0, 0, 0, 0, 0, 0, 0};
  } else {
    int hi = 2 * (ho - 1) + 1, wi = 2 * (wo - 1) + 1;
    const unsigned short* p =
        (const unsigned short*)x + (((size_t)(b * W2I + hi) * W2I) + wi) * C + c8 * 8;
    us8 v0 = *(const us8*)p;
    us8 v1 = *(const us8*)(p + C);
    us8 v2 = *(const us8*)(p + (size_t)W2I * C);
    us8 v3 = *(const us8*)(p + (size_t)W2I * C + C);
#pragma unroll
    for (int e = 0; e < 8; ++e) {
      unsigned short a = v0[e] > v1[e] ? v0[e] : v1[e];
      unsigned short c = v2[e] > v3[e] ? v2[e] : v3[e];
      out[e] = a > c ? a : c;
    }
  }
  *(us8*)((unsigned short*)y + (((size_t)(b * W2O + ho) * W2O) + wo) * C + c8 * 8) = out;
}

// 1x1 conv 256 -> 10 + bias (no relu), 16x16 spatial, fp32
__global__ void head2_kernel(const float* __restrict__ x, const float* __restrict__ wk,
                             const float* __restrict__ bias, float* __restrict__ y) {
  int h = blockIdx.x, b = blockIdx.y;
  int t = threadIdx.x;
  int co = t & 15, w = t >> 4;
  if (co >= 10) return;
  const float* xr = x + ((size_t)(b * 16 + h) * 16 + w) * 256;
  float acc = 0.f;
#pragma unroll 4
  for (int ci = 0; ci < 256; ci += 4) {
    float4 in4 = *(const float4*)(xr + ci);
    acc = fmaf(in4.x, wk[(ci + 0) * 10 + co], acc);
    acc = fmaf(in4.y, wk[(ci + 1) * 10 + co], acc);
    acc = fmaf(in4.z, wk[(ci + 2) * 10 + co], acc);
    acc = fmaf(in4.w, wk[(ci + 3) * 10 + co], acc);
  }
  y[((size_t)(b * 16 + h) * 16 + w) * 10 + co] = acc + bias[co];
}

// scatter reduced 16x16 head output -> full 27x31 NCHW output
__global__ void scatter_kernel(const float* __restrict__ y, float* __restrict__ out) {
  int idx = blockIdx.x * 256 + threadIdx.x;
  if (idx >= 4 * 10 * 27 * 31) return;
  int c = idx % 31;
  int r = (idx / 31) % 27;
  int ch = (idx / (31 * 27)) % 10;
  int b = idx / (31 * 27 * 10);
  int rr = (r <= 7) ? r : ((r >= 20) ? r - 11 : 7);
  int cc = (c <= 7) ? c : ((c >= 24) ? c - 15 : 7);
  out[idx] = y[((size_t)(b * 16 + rr) * 16 + cc) * 10 + ch];
}

// ---------------------------------------------------------------------------
extern "C" void kernel_launch(void* const* d_in, const int* in_sizes, int n_in,
                              void* d_out, int out_size, void* d_ws, size_t ws_size,
                              hipStream_t stream) {
  (void)in_sizes; (void)n_in; (void)out_size; (void)ws_size;
  const float* pillars = (const float*)d_in[0];
  const float* w1 = (const float*)d_in[1];
  const float* b1 = (const float*)d_in[2];
  const float* s1 = (const float*)d_in[3];
  const float* t1 = (const float*)d_in[4];
  const float* w2 = (const float*)d_in[5];
  const float* b2 = (const float*)d_in[6];
  const float* s2 = (const float*)d_in[7];
  const float* t2 = (const float*)d_in[8];
  const float* ck[6], *cbv[6], *csv[6], *ctv[6];
  for (int i = 0; i < 6; ++i) {
    ck[i]  = (const float*)d_in[9 + i * 4];
    cbv[i] = (const float*)d_in[10 + i * 4];
    csv[i] = (const float*)d_in[11 + i * 4];
    ctv[i] = (const float*)d_in[12 + i * 4];
  }
  const float* hk1 = (const float*)d_in[33];
  const float* hb1 = (const float*)d_in[34];
  const float* hk2 = (const float*)d_in[35];
  const float* hb2 = (const float*)d_in[36];
  const int* num_points = (const int*)d_in[37];
  float* out = (float*)d_out;

  // ---- ws layout (cursor allocator, deterministic) ----
  char* wsb = (char*)d_ws;
  size_t off = 0;
  auto alloc = [&](size_t n) { char* p = wsb + off; off = (off + n + 255) & ~(size_t)255; return p; };
  float*  kpart  = (float*)alloc(12582912);          // [3][16384][64] f32 max
  float*  ppart  = (float*)alloc(1536000);
  int*    pcnt   = (int*)alloc(24000);
  float*  mean   = (float*)alloc(1024);
  __bf16* wfrag  = (__bf16*)alloc(12288);
  float4* cfrag  = (float4*)alloc(4096);
  float*  h2out  = (float*)alloc(40960);
  __bf16* wT     = (__bf16*)alloc(3538944);
  __bf16* A64    = (__bf16*)alloc(2230272);
  __bf16* B64    = (__bf16*)alloc(2230272);
  __bf16* PL64   = (__bf16*)alloc(591872);
  __bf16* C128A  = (__bf16*)alloc(1183744);
  __bf16* C128B  = (__bf16*)alloc(1183744);
  __bf16* PL128  = (__bf16*)alloc(331776);
  __bf16* C256A  = (__bf16*)alloc(663552);
  __bf16* C256B  = (__bf16*)alloc(663552);
  float*  h1out  = (float*)alloc(1048576);

  __bf16* wt1 = wT + 0;       __bf16* wt2 = wT + 36864;
  __bf16* wt3 = wT + 73728;   __bf16* wt4 = wT + 147456;
  __bf16* wt5 = wT + 294912;  __bf16* wt6 = wT + 589824;
  __bf16* wth = wT + 1179648;

  setup_kernel<<<1, 64, 0, stream>>>(w1, b1, s1, t1, w2, b2, s2, t2, wfrag, cfrag);
  convw_kernel<<<6912, 256, 0, stream>>>(ck[0], ck[1], ck[2], ck[3], ck[4], ck[5],
                                         hk1, wT);
  zero_borders_kernel<<<183, 256, 0, stream>>>(A64, B64, C128A, C128B, C256A, C256B);

  pillar_kernel<<<6000, 256, 0, stream>>>(pillars, num_points, wfrag, cfrag,
                                          ppart, pcnt);
  mean_kernel<<<4, 256, 0, stream>>>(ppart, pcnt, mean);
  broadcast_kernel<<<512, 256, 0, stream>>>(mean, A64);

  // backbone: kconv (K-split partials) + reduce (BN/ReLU/pack) per layer
  kconv_kernel<64, 64, 64><<<384, 256, 0, stream>>>(A64, wt1, kpart);
  reduce_kernel<64, 64, true, false><<<1024, 256, 0, stream>>>(
      kpart, cbv[0], csv[0], ctv[0], B64, nullptr);
  kconv_kernel<64, 64, 64><<<384, 256, 0, stream>>>(B64, wt2, kpart);
  reduce_kernel<64, 64, true, false><<<1024, 256, 0, stream>>>(
      kpart, cbv[1], csv[1], ctv[1], A64, nullptr);
  pool_kernel<64, 64><<<145, 256, 0, stream>>>(A64, PL64);        // -> [34][34][64]
  kconv_kernel<64, 128, 32><<<192, 256, 0, stream>>>(PL64, wt3, kpart);
  reduce_kernel<128, 32, true, false><<<512, 256, 0, stream>>>(
      kpart, cbv[2], csv[2], ctv[2], C128A, nullptr);
  kconv_kernel<128, 128, 32><<<192, 256, 0, stream>>>(C128A, wt4, kpart);
  reduce_kernel<128, 32, true, false><<<512, 256, 0, stream>>>(
      kpart, cbv[3], csv[3], ctv[3], C128B, nullptr);
  pool_kernel<128, 32><<<81, 256, 0, stream>>>(C128B, PL128);     // -> [18][18][128]
  kconv_kernel<128, 256, 16><<<96, 256, 0, stream>>>(PL128, wt5, kpart);
  reduce_kernel<256, 16, true, false><<<256, 256, 0, stream>>>(
      kpart, cbv[4], csv[4], ctv[4], C256A, nullptr);
  kconv_kernel<256, 256, 16><<<96, 256, 0, stream>>>(C256A, wt6, kpart);
  reduce_kernel<256, 16, true, false><<<256, 256, 0, stream>>>(
      kpart, cbv[5], csv[5], ctv[5], C256B, nullptr);
  kconv_kernel<256, 256, 16><<<96, 256, 0, stream>>>(C256B, wth, kpart);
  reduce_kernel<256, 16, false, true><<<256, 256, 0, stream>>>(
      kpart, hb1, nullptr, nullptr, nullptr, h1out);

  head2_kernel<<<dim3(16, 4), 256, 0, stream>>>(h1out, hk2, hb2, h2out);
  scatter_kernel<<<131, 256, 0, stream>>>(h2out, out);
}

// Round 5
// 340.752 us; speedup vs baseline: 3.0623x; 1.0927x over previous
//
#include <hip/hip_runtime.h>

// ---------- types ----------
typedef __bf16 vbf8 __attribute__((ext_vector_type(8)));
typedef __bf16 vbf4 __attribute__((ext_vector_type(4)));
typedef unsigned short us8 __attribute__((ext_vector_type(8)));
typedef float f32x4 __attribute__((ext_vector_type(4)));
typedef float f32x4u __attribute__((ext_vector_type(4), aligned(4)));

// ---------------------------------------------------------------------------
// setup: precompute MFMA weight fragments for the pillar net.
//  L1 (swapped): A = W1^T with custom row order c(m,row) so that D1 registers
//  land exactly in L2's A-fragment layout. BN1 scale folded into W1; BN1
//  shift appended as bias row k=9 (input feature 9 == 1.0).
//  L2: B = W2 (normal), BN2 scale folded in; BN2 shift via MFMA C-operand.
// wfrag[12][64][8] bf16; be2f[4][64] float.
// ---------------------------------------------------------------------------
__global__ void setup_kernel(const float* __restrict__ w1, const float* __restrict__ b1,
                             const float* __restrict__ s1, const float* __restrict__ t1,
                             const float* __restrict__ w2, const float* __restrict__ b2,
                             const float* __restrict__ s2, const float* __restrict__ t2,
                             __bf16* __restrict__ wfrag, float* __restrict__ be2f) {
  int l = threadIdx.x;                       // 0..63
  int s = l & 15, g = l >> 4;
#pragma unroll
  for (int m = 0; m < 4; ++m) {
    // L1 A-frag, m-tile m: row = l&15, k = g*8+e
    int c = 32 * (m & 1) + 8 * (s >> 2) + 4 * (m >> 1) + (s & 3);
#pragma unroll
    for (int e = 0; e < 8; ++e) {
      int k = g * 8 + e;
      float v = 0.f;
      if (k < 9)       v = w1[k * 64 + c] * s1[c];
      else if (k == 9) v = fmaf(b1[c], s1[c], t1[c]);
      wfrag[(m * 64 + l) * 8 + e] = (__bf16)v;
    }
    // L2 B-frags: k = g*8+e (+32), n-col co = s + 16m
    int co = s + 16 * m;
#pragma unroll
    for (int e = 0; e < 8; ++e) {
      int k = g * 8 + e;
      wfrag[((4 + m) * 64 + l) * 8 + e] = (__bf16)(w2[k * 64 + co] * s2[co]);
      wfrag[((8 + m) * 64 + l) * 8 + e] = (__bf16)(w2[(32 + k) * 64 + co] * s2[co]);
    }
    be2f[m * 64 + l] = fmaf(b2[co], s2[co], t2[co]);
  }
}

// ---------------------------------------------------------------------------
// weight transpose+convert, LDS-tiled (coalesced read AND write):
// HWIO [tap][ci][co] f32 -> wT [tap][co][ci] bf16.  432 tiles of 64x64.
// ---------------------------------------------------------------------------
__global__ __launch_bounds__(256) void convw_kernel(
    const float* __restrict__ k1, const float* __restrict__ k2,
    const float* __restrict__ k3, const float* __restrict__ k4,
    const float* __restrict__ k5, const float* __restrict__ k6,
    const float* __restrict__ kh, __bf16* __restrict__ wT) {
  __shared__ float tile[64][65];
  const int tCI[7]    = {64, 64, 64, 128, 128, 256, 256};
  const int tCO[7]    = {64, 64, 128, 128, 256, 256, 256};
  const int tOFF[7]   = {0, 36864, 73728, 147456, 294912, 589824, 1179648};
  const int tTILES[7] = {9, 9, 18, 36, 72, 144, 144};
  int bid = blockIdx.x;
  int ti = 0, acc = 0;
  while (ti < 6 && bid >= acc + tTILES[ti]) { acc += tTILES[ti]; ++ti; }
  int lt = bid - acc;
  int CI = tCI[ti], CO = tCO[ti];
  const float* src;
  if (ti == 0) src = k1; else if (ti == 1) src = k2; else if (ti == 2) src = k3;
  else if (ti == 3) src = k4; else if (ti == 4) src = k5; else if (ti == 5) src = k6;
  else src = kh;
  int cot = CO / 64, tpt = (CI / 64) * cot;
  int tap = lt / tpt; int r2 = lt - tap * tpt;
  int ci0 = (r2 / cot) * 64, co0 = (r2 % cot) * 64;
  const float* sp = src + (size_t)(tap * CI + ci0) * CO + co0;
  int t = threadIdx.x;
  int lr = t >> 6, lc = t & 63;
#pragma unroll
  for (int rr = 0; rr < 64; rr += 4)
    tile[rr + lr][lc] = sp[(size_t)(rr + lr) * CO + lc];
  __syncthreads();
  __bf16* dst = wT + tOFF[ti] + ((size_t)tap * CO + co0) * CI + ci0;
#pragma unroll
  for (int rr = 0; rr < 64; rr += 4)
    dst[(size_t)(rr + lr) * CI + lc] = (__bf16)tile[lc][rr + lr];
}

// ---------------------------------------------------------------------------
// zero the 1-px borders of all padded activation buffers (fused, one launch)
// ---------------------------------------------------------------------------
__global__ void zero_borders_kernel(__bf16* __restrict__ a64, __bf16* __restrict__ b64,
                                    __bf16* __restrict__ c128a, __bf16* __restrict__ c128b,
                                    __bf16* __restrict__ c256a, __bf16* __restrict__ c256b) {
  int idx = blockIdx.x * 256 + threadIdx.x;
  __bf16* buf; int H2, C, p;
  if (idx < 34848)       { buf = (idx < 17424) ? a64 : b64;     H2 = 66; C = 64;  p = idx % 17424; }
  else if (idx < 44096)  { int q = idx - 34848; buf = (q < 4624) ? c128a : c128b; H2 = 34; C = 128; p = q % 4624; }
  else if (idx < 46688)  { int q = idx - 44096; buf = (q < 1296) ? c256a : c256b; H2 = 18; C = 256; p = q % 1296; }
  else return;
  int w = p % H2; int h = (p / H2) % H2;
  if (h != 0 && h != H2 - 1 && w != 0 && w != H2 - 1) return;
  us8 zz = {0, 0, 0, 0, 0, 0, 0, 0};
  __bf16* q = buf + (size_t)p * C;
  for (int c = 0; c < C; c += 8) *(us8*)(q + c) = zz;
}

// ---------------------------------------------------------------------------
// Stage A: pillar feature net, register-only inter-layer transpose.
//  L1: d1[m] = mfma(A=w1f[m] (custom row order), B=Xt)  -> D[ch][pt]
//  repack (pure regs): a2f0/a2f1 = relu(d1) as L2 A-frags (pt=lane&15)
//  L2: d2[n] = mfma(A=a2f, B=w2f[n], C=be2)             -> D[pt][ch]
// 2 pillars per wave; 6000 blocks x 4 waves.
// ---------------------------------------------------------------------------
__global__ __launch_bounds__(256) void pillar_kernel(
    const float* __restrict__ pil, const int* __restrict__ npt,
    const __bf16* __restrict__ wfrag, const float* __restrict__ be2f,
    float* __restrict__ partial, int* __restrict__ pcnt)
{
  __shared__ float redf[4][64];
  __shared__ int redc[4];
  const int tid = threadIdx.x;
  const int wv = tid >> 6, lane = tid & 63;
  const int s = lane & 15, g = lane >> 4;
  const int wid = blockIdx.x * 4 + wv;       // 0..23999
  const int b = wid / 6000;
  const int p0 = (wid - b * 6000) * 2;

  vbf8 w1f[4], w2f0[4], w2f1[4];
  float be2[4];
#pragma unroll
  for (int m = 0; m < 4; ++m) {
    w1f[m]  = *(const vbf8*)(wfrag + ((0 + m) * 64 + lane) * 8);
    w2f0[m] = *(const vbf8*)(wfrag + ((4 + m) * 64 + lane) * 8);
    w2f1[m] = *(const vbf8*)(wfrag + ((8 + m) * 64 + lane) * 8);
    be2[m] = be2f[m * 64 + lane];
  }

  float fsum[4] = {0.f, 0.f, 0.f, 0.f};
  int cnt = 0;

  for (int i = 0; i < 2; ++i) {
    int pidx = b * 12000 + p0 + i;
    int np = npt[pidx];
    if (np <= 0) continue;     // wave-uniform
    ++cnt;
    float feat[4][4];
#pragma unroll
    for (int n = 0; n < 4; ++n)
#pragma unroll
      for (int r = 0; r < 4; ++r) feat[n][r] = 0.f;

    int ngrp = (np + 15) >> 4;
    const float* pbase = pil + (size_t)pidx * 900;
    for (int grp = 0; grp < ngrp; ++grp) {
      // B1-frag: k = g*8+e (feature; k=9 is the bias row == 1.0), n = point s
      int pt = grp * 16 + s; pt = min(pt, 99);
      const float* ptp = pbase + pt * 9;
      f32x4u lo = *(const f32x4u*)ptp;
      f32x4u hi = *(const f32x4u*)(ptp + 4);
      float v8 = ptp[8];
      vbf8 b1f;
      b1f[0] = (__bf16)(g == 0 ? lo[0] : (g == 1 ? v8 : 0.f));
      b1f[1] = (__bf16)(g == 0 ? lo[1] : (g == 1 ? 1.0f : 0.f));
      b1f[2] = (__bf16)(g == 0 ? lo[2] : 0.f);
      b1f[3] = (__bf16)(g == 0 ? lo[3] : 0.f);
      b1f[4] = (__bf16)(g == 0 ? hi[0] : 0.f);
      b1f[5] = (__bf16)(g == 0 ? hi[1] : 0.f);
      b1f[6] = (__bf16)(g == 0 ? hi[2] : 0.f);
      b1f[7] = (__bf16)(g == 0 ? hi[3] : 0.f);

      const f32x4 z = {0.f, 0.f, 0.f, 0.f};
      f32x4 d1[4];
#pragma unroll
      for (int m = 0; m < 4; ++m)
        d1[m] = __builtin_amdgcn_mfma_f32_16x16x32_bf16(w1f[m], b1f, z, 0, 0, 0);

      // ReLU + bf16, straight into L2 A-fragments (register-only repack):
      // channel of d1[m][r] = 32*(m&1) + 8g + 4*(m>>1) + r
      vbf8 a2f0, a2f1;
#pragma unroll
      for (int r = 0; r < 4; ++r) {
        a2f0[r]     = (__bf16)fmaxf(d1[0][r], 0.f);
        a2f1[r]     = (__bf16)fmaxf(d1[1][r], 0.f);
        a2f0[4 + r] = (__bf16)fmaxf(d1[2][r], 0.f);
        a2f1[4 + r] = (__bf16)fmaxf(d1[3][r], 0.f);
      }

      f32x4 d2[4];
#pragma unroll
      for (int n = 0; n < 4; ++n) {
        f32x4 cb = {be2[n], be2[n], be2[n], be2[n]};
        d2[n] = __builtin_amdgcn_mfma_f32_16x16x32_bf16(a2f0, w2f0[n], cb, 0, 0, 0);
        d2[n] = __builtin_amdgcn_mfma_f32_16x16x32_bf16(a2f1, w2f1[n], d2[n], 0, 0, 0);
      }
      // masked max (relu deferred to the end: max(0,...) via feat init 0)
      if (((grp + 1) << 4) <= np) {        // full group, wave-uniform
#pragma unroll
        for (int n = 0; n < 4; ++n)
#pragma unroll
          for (int r = 0; r < 4; ++r) feat[n][r] = fmaxf(feat[n][r], d2[n][r]);
      } else {
#pragma unroll
        for (int n = 0; n < 4; ++n)
#pragma unroll
          for (int r = 0; r < 4; ++r) {
            float vv = (grp * 16 + 4 * g + r < np) ? d2[n][r] : 0.f;
            feat[n][r] = fmaxf(feat[n][r], vv);
          }
      }
    }
#pragma unroll
    for (int n = 0; n < 4; ++n) {
      float m = fmaxf(fmaxf(feat[n][0], feat[n][1]), fmaxf(feat[n][2], feat[n][3]));
      m = fmaxf(m, __shfl_xor(m, 16));
      m = fmaxf(m, __shfl_xor(m, 32));
      fsum[n] += m;
    }
  }
  if (g == 0) {
#pragma unroll
    for (int n = 0; n < 4; ++n) redf[wv][s + 16 * n] = fsum[n];
  }
  if (lane == 0) redc[wv] = cnt;
  __syncthreads();
  if (tid < 64) {
    float tot = redf[0][tid] + redf[1][tid] + redf[2][tid] + redf[3][tid];
    partial[blockIdx.x * 64 + tid] = tot;
    if (tid == 0) pcnt[blockIdx.x] = redc[0] + redc[1] + redc[2] + redc[3];
  }
}

// finish the mean: 4 blocks (one per batch), 1500 partial blocks each
__global__ void mean_kernel(const float* __restrict__ partial,
                            const int* __restrict__ pcnt,
                            float* __restrict__ mean) {
  int b = blockIdx.x, t = threadIdx.x;
  int c = t & 63, q = t >> 6;
  float sum = 0.f;
  for (int w = q; w < 1500; w += 4) sum += partial[(b * 1500 + w) * 64 + c];
  int cl = 0;
  for (int w = t; w < 1500; w += 256) cl += pcnt[b * 1500 + w];
  __shared__ float sh[256];
  __shared__ int shc[256];
  sh[t] = sum; shc[t] = cl;
  __syncthreads();
  for (int o = 128; o > 0; o >>= 1) {
    if (t < o) shc[t] += shc[t + o];
    __syncthreads();
  }
  if (t < 64) {
    float tot = sh[t] + sh[t + 64] + sh[t + 128] + sh[t + 192];
    mean[b * 64 + t] = tot / (float)(shc[0] > 0 ? shc[0] : 1);
  }
}

// broadcast mean -> x0 interior of [4][66][66][64] bf16 padded
__global__ void broadcast_kernel(const float* __restrict__ mean,
                                 __bf16* __restrict__ x0) {
  int idx = blockIdx.x * 256 + threadIdx.x;   // 131072
  int c8 = idx & 7; int rest = idx >> 3;
  int w = rest & 63; rest >>= 6;
  int h = rest & 63; int b = rest >> 6;
  const float* mb = mean + b * 64 + c8 * 8;
  vbf8 v;
#pragma unroll
  for (int e = 0; e < 8; ++e) v[e] = (__bf16)mb[e];
  *(vbf8*)(x0 + (((size_t)(b * 66 + h + 1) * 66) + (w + 1)) * 64 + c8 * 8) = v;
}

// ---------------------------------------------------------------------------
// K-split implicit-GEMM 3x3 conv, bf16 MFMA, fp32 partials (no epilogue).
// wave-task = ((mt * NT + nt) * 3 + kg); wave tile = M 32 x N 64, taps {3kg..}
// ---------------------------------------------------------------------------
template <int CIN, int COUT, int HW>
__global__ __launch_bounds__(256) void kconv_kernel(
    const __bf16* __restrict__ x, const __bf16* __restrict__ wt,
    float* __restrict__ kpart)
{
  constexpr int H2 = HW + 2;
  constexpr int NT = COUT / 64;
  constexpr int KC = CIN / 32;
  constexpr int MTOT = 4 * HW * HW;
  constexpr int LOG = (HW == 64) ? 6 : (HW == 32) ? 5 : 4;
  const int tid = threadIdx.x, wv = tid >> 6, lane = tid & 63;
  const int s = lane & 15, g = lane >> 4;
  const int task = blockIdx.x * 4 + wv;
  const int kg = task % 3;
  const int t2 = task / 3;
  const int nt = t2 % NT;
  const int mt = t2 / NT;
  const int m0 = mt * 32;
  const int b = m0 >> (2 * LOG);
  const int mb = m0 - (b << (2 * LOG));

  size_t arow[2];
#pragma unroll
  for (int mf = 0; mf < 2; ++mf) {
    int m = mb + mf * 16 + s;
    int hh = m >> LOG, ww = m & (HW - 1);
    arow[mf] = ((size_t)(b * H2 + hh) * H2 + ww) * CIN;
  }

  f32x4 acc[2][4];
#pragma unroll
  for (int mf = 0; mf < 2; ++mf)
#pragma unroll
    for (int nf = 0; nf < 4; ++nf) acc[mf][nf] = (f32x4){0.f, 0.f, 0.f, 0.f};

#pragma unroll
  for (int j = 0; j < 3; ++j) {
    const int tap = kg * 3 + j;
    const int dh = tap / 3, dw = tap % 3;
    const size_t aoff = ((size_t)dh * H2 + dw) * CIN + 8 * g;
    const __bf16* wtap = wt + ((size_t)tap * COUT + nt * 64) * CIN + 8 * g;
#pragma unroll 2
    for (int ck = 0; ck < KC; ++ck) {
      vbf8 a0 = *(const vbf8*)(x + arow[0] + aoff + ck * 32);
      vbf8 a1 = *(const vbf8*)(x + arow[1] + aoff + ck * 32);
#pragma unroll
      for (int nf = 0; nf < 4; ++nf) {
        vbf8 bb = *(const vbf8*)(wtap + (size_t)(nf * 16 + s) * CIN + ck * 32);
        acc[0][nf] = __builtin_amdgcn_mfma_f32_16x16x32_bf16(a0, bb, acc[0][nf], 0, 0, 0);
        acc[1][nf] = __builtin_amdgcn_mfma_f32_16x16x32_bf16(a1, bb, acc[1][nf], 0, 0, 0);
      }
    }
  }

  float* kp = kpart + (size_t)kg * MTOT * COUT;
#pragma unroll
  for (int mf = 0; mf < 2; ++mf)
#pragma unroll
    for (int nf = 0; nf < 4; ++nf) {
      int co = nt * 64 + nf * 16 + s;
#pragma unroll
      for (int r = 0; r < 4; ++r) {
        int m = m0 + mf * 16 + 4 * g + r;
        kp[(size_t)m * COUT + co] = acc[mf][nf][r];
      }
    }
}

// ---------------------------------------------------------------------------
// reduce K-split partials + BN/bias + ReLU -> padded bf16 (or flat f32)
// ---------------------------------------------------------------------------
template <int COUT, int HW, bool HAS_BN, bool OUT_F32>
__global__ __launch_bounds__(256) void reduce_kernel(
    const float* __restrict__ kpart, const float* __restrict__ cb,
    const float* __restrict__ cs, const float* __restrict__ ct,
    __bf16* __restrict__ ypad, float* __restrict__ yf32)
{
  constexpr int H2 = HW + 2;
  constexpr int MTOT = 4 * HW * HW;
  constexpr int CQ = COUT / 4;
  constexpr int LOG = (HW == 64) ? 6 : (HW == 32) ? 5 : 4;
  int idx = blockIdx.x * 256 + threadIdx.x;
  int cq = idx % CQ; int m = idx / CQ;
  int co0 = cq * 4;
  const f32x4* f4 = (const f32x4*)kpart;
  f32x4 v = f4[(size_t)m * CQ + cq];
  f32x4 v1 = f4[((size_t)MTOT + m) * CQ + cq];
  f32x4 v2 = f4[((size_t)2 * MTOT + m) * CQ + cq];
  v += v1 + v2;
  f32x4 r;
  if (HAS_BN) {
    f32x4 sc = *(const f32x4*)(cs + co0);
    f32x4 bb = *(const f32x4*)(cb + co0);
    f32x4 tt = *(const f32x4*)(ct + co0);
#pragma unroll
    for (int e = 0; e < 4; ++e) r[e] = fmaxf(fmaf(v[e], sc[e], fmaf(bb[e], sc[e], tt[e])), 0.f);
  } else {
    f32x4 bb = *(const f32x4*)(cb + co0);
#pragma unroll
    for (int e = 0; e < 4; ++e) r[e] = fmaxf(v[e] + bb[e], 0.f);
  }
  if constexpr (OUT_F32) {
    *(f32x4*)(yf32 + (size_t)m * COUT + co0) = r;
  } else {
    int b = m >> (2 * LOG);
    int mm = m - (b << (2 * LOG));
    int hh = mm >> LOG, ww = mm & (HW - 1);
    vbf4 o;
#pragma unroll
    for (int e = 0; e < 4; ++e) o[e] = (__bf16)r[e];
    *(vbf4*)(ypad + (((size_t)(b * H2 + hh + 1) * H2) + ww + 1) * COUT + co0) = o;
  }
}

// 2x2 max pool bf16 padded -> bf16 padded (writes its own zero borders).
template <int C, int HI>
__global__ void pool_kernel(const __bf16* __restrict__ x, __bf16* __restrict__ y) {
  constexpr int HO = HI / 2, W2I = HI + 2, W2O = HO + 2, C8 = C / 8;
  int idx = blockIdx.x * 256 + threadIdx.x;
  if (idx >= 4 * W2O * W2O * C8) return;
  int c8 = idx % C8; int rest = idx / C8;
  int wo = rest % W2O; rest /= W2O;
  int ho = rest % W2O; int b = rest / W2O;
  us8 out;
  if (ho == 0 || ho == W2O - 1 || wo == 0 || wo == W2O - 1) {
    out = (us8){0, 0, 0, 0, 0, 0, 0, 0};
  } else {
    int hi = 2 * (ho - 1) + 1, wi = 2 * (wo - 1) + 1;
    const unsigned short* p =
        (const unsigned short*)x + (((size_t)(b * W2I + hi) * W2I) + wi) * C + c8 * 8;
    us8 v0 = *(const us8*)p;
    us8 v1 = *(const us8*)(p + C);
    us8 v2 = *(const us8*)(p + (size_t)W2I * C);
    us8 v3 = *(const us8*)(p + (size_t)W2I * C + C);
#pragma unroll
    for (int e = 0; e < 8; ++e) {
      unsigned short a = v0[e] > v1[e] ? v0[e] : v1[e];
      unsigned short c = v2[e] > v3[e] ? v2[e] : v3[e];
      out[e] = a > c ? a : c;
    }
  }
  *(us8*)((unsigned short*)y + (((size_t)(b * W2O + ho) * W2O) + wo) * C + c8 * 8) = out;
}

// 1x1 conv 256 -> 10 + bias (no relu), 16x16 spatial, fp32
__global__ void head2_kernel(const float* __restrict__ x, const float* __restrict__ wk,
                             const float* __restrict__ bias, float* __restrict__ y) {
  int h = blockIdx.x, b = blockIdx.y;
  int t = threadIdx.x;
  int co = t & 15, w = t >> 4;
  if (co >= 10) return;
  const float* xr = x + ((size_t)(b * 16 + h) * 16 + w) * 256;
  float acc = 0.f;
#pragma unroll 4
  for (int ci = 0; ci < 256; ci += 4) {
    float4 in4 = *(const float4*)(xr + ci);
    acc = fmaf(in4.x, wk[(ci + 0) * 10 + co], acc);
    acc = fmaf(in4.y, wk[(ci + 1) * 10 + co], acc);
    acc = fmaf(in4.z, wk[(ci + 2) * 10 + co], acc);
    acc = fmaf(in4.w, wk[(ci + 3) * 10 + co], acc);
  }
  y[((size_t)(b * 16 + h) * 16 + w) * 10 + co] = acc + bias[co];
}

// scatter reduced 16x16 head output -> full 27x31 NCHW output
__global__ void scatter_kernel(const float* __restrict__ y, float* __restrict__ out) {
  int idx = blockIdx.x * 256 + threadIdx.x;
  if (idx >= 4 * 10 * 27 * 31) return;
  int c = idx % 31;
  int r = (idx / 31) % 27;
  int ch = (idx / (31 * 27)) % 10;
  int b = idx / (31 * 27 * 10);
  int rr = (r <= 7) ? r : ((r >= 20) ? r - 11 : 7);
  int cc = (c <= 7) ? c : ((c >= 24) ? c - 15 : 7);
  out[idx] = y[((size_t)(b * 16 + rr) * 16 + cc) * 10 + ch];
}

// ---------------------------------------------------------------------------
extern "C" void kernel_launch(void* const* d_in, const int* in_sizes, int n_in,
                              void* d_out, int out_size, void* d_ws, size_t ws_size,
                              hipStream_t stream) {
  (void)in_sizes; (void)n_in; (void)out_size; (void)ws_size;
  const float* pillars = (const float*)d_in[0];
  const float* w1 = (const float*)d_in[1];
  const float* b1 = (const float*)d_in[2];
  const float* s1 = (const float*)d_in[3];
  const float* t1 = (const float*)d_in[4];
  const float* w2 = (const float*)d_in[5];
  const float* b2 = (const float*)d_in[6];
  const float* s2 = (const float*)d_in[7];
  const float* t2 = (const float*)d_in[8];
  const float* ck[6], *cbv[6], *csv[6], *ctv[6];
  for (int i = 0; i < 6; ++i) {
    ck[i]  = (const float*)d_in[9 + i * 4];
    cbv[i] = (const float*)d_in[10 + i * 4];
    csv[i] = (const float*)d_in[11 + i * 4];
    ctv[i] = (const float*)d_in[12 + i * 4];
  }
  const float* hk1 = (const float*)d_in[33];
  const float* hb1 = (const float*)d_in[34];
  const float* hk2 = (const float*)d_in[35];
  const float* hb2 = (const float*)d_in[36];
  const int* num_points = (const int*)d_in[37];
  float* out = (float*)d_out;

  // ---- ws layout (cursor allocator, deterministic) ----
  char* wsb = (char*)d_ws;
  size_t off = 0;
  auto alloc = [&](size_t n) { char* p = wsb + off; off = (off + n + 255) & ~(size_t)255; return p; };
  float*  kpart  = (float*)alloc(12582912);          // [3][16384][64] f32 max
  float*  ppart  = (float*)alloc(1536000);
  int*    pcnt   = (int*)alloc(24000);
  float*  mean   = (float*)alloc(1024);
  __bf16* wfrag  = (__bf16*)alloc(12288);
  float*  be2f   = (float*)alloc(1024);
  float*  h2out  = (float*)alloc(40960);
  __bf16* wT     = (__bf16*)alloc(3538944);
  __bf16* A64    = (__bf16*)alloc(2230272);
  __bf16* B64    = (__bf16*)alloc(2230272);
  __bf16* PL64   = (__bf16*)alloc(591872);
  __bf16* C128A  = (__bf16*)alloc(1183744);
  __bf16* C128B  = (__bf16*)alloc(1183744);
  __bf16* PL128  = (__bf16*)alloc(331776);
  __bf16* C256A  = (__bf16*)alloc(663552);
  __bf16* C256B  = (__bf16*)alloc(663552);
  float*  h1out  = (float*)alloc(1048576);

  __bf16* wt1 = wT + 0;       __bf16* wt2 = wT + 36864;
  __bf16* wt3 = wT + 73728;   __bf16* wt4 = wT + 147456;
  __bf16* wt5 = wT + 294912;  __bf16* wt6 = wT + 589824;
  __bf16* wth = wT + 1179648;

  setup_kernel<<<1, 64, 0, stream>>>(w1, b1, s1, t1, w2, b2, s2, t2, wfrag, be2f);
  convw_kernel<<<432, 256, 0, stream>>>(ck[0], ck[1], ck[2], ck[3], ck[4], ck[5],
                                        hk1, wT);
  zero_borders_kernel<<<183, 256, 0, stream>>>(A64, B64, C128A, C128B, C256A, C256B);

  pillar_kernel<<<6000, 256, 0, stream>>>(pillars, num_points, wfrag, be2f,
                                          ppart, pcnt);
  mean_kernel<<<4, 256, 0, stream>>>(ppart, pcnt, mean);
  broadcast_kernel<<<512, 256, 0, stream>>>(mean, A64);

  // backbone: kconv (K-split partials) + reduce (BN/ReLU/pack) per layer
  kconv_kernel<64, 64, 64><<<384, 256, 0, stream>>>(A64, wt1, kpart);
  reduce_kernel<64, 64, true, false><<<1024, 256, 0, stream>>>(
      kpart, cbv[0], csv[0], ctv[0], B64, nullptr);
  kconv_kernel<64, 64, 64><<<384, 256, 0, stream>>>(B64, wt2, kpart);
  reduce_kernel<64, 64, true, false><<<1024, 256, 0, stream>>>(
      kpart, cbv[1], csv[1], ctv[1], A64, nullptr);
  pool_kernel<64, 64><<<145, 256, 0, stream>>>(A64, PL64);        // -> [34][34][64]
  kconv_kernel<64, 128, 32><<<192, 256, 0, stream>>>(PL64, wt3, kpart);
  reduce_kernel<128, 32, true, false><<<512, 256, 0, stream>>>(
      kpart, cbv[2], csv[2], ctv[2], C128A, nullptr);
  kconv_kernel<128, 128, 32><<<192, 256, 0, stream>>>(C128A, wt4, kpart);
  reduce_kernel<128, 32, true, false><<<512, 256, 0, stream>>>(
      kpart, cbv[3], csv[3], ctv[3], C128B, nullptr);
  pool_kernel<128, 32><<<81, 256, 0, stream>>>(C128B, PL128);     // -> [18][18][128]
  kconv_kernel<128, 256, 16><<<96, 256, 0, stream>>>(PL128, wt5, kpart);
  reduce_kernel<256, 16, true, false><<<256, 256, 0, stream>>>(
      kpart, cbv[4], csv[4], ctv[4], C256A, nullptr);
  kconv_kernel<256, 256, 16><<<96, 256, 0, stream>>>(C256A, wt6, kpart);
  reduce_kernel<256, 16, true, false><<<256, 256, 0, stream>>>(
      kpart, cbv[5], csv[5], ctv[5], C256B, nullptr);
  kconv_kernel<256, 256, 16><<<96, 256, 0, stream>>>(C256B, wth, kpart);
  reduce_kernel<256, 16, false, true><<<256, 256, 0, stream>>>(
      kpart, hb1, nullptr, nullptr, nullptr, h1out);

  head2_kernel<<<dim3(16, 4), 256, 0, stream>>>(h1out, hk2, hb2, h2out);
  scatter_kernel<<<131, 256, 0, stream>>>(h2out, out);
}